// Round 7
// baseline (857.532 us; speedup 1.0000x reference)
//
#include <hip/hip_runtime.h>
#include <math.h>

#define N_NODES 50000
#define E_EDGES 800000
#define IN_DIM 128
#define HEADS 4
#define OUT_DIM 32
#define HD 128          // HEADS*OUT_DIM
#define LEAKY 0.4f
#define BN_EPS 1e-5f

// bucketed counting sort params: bucket = tgt >> 7 (128 targets/bucket)
#define BSH 7
#define NB ((N_NODES + 127) >> BSH)     // 391
#define FB 196                           // fill block count
#define FCH 4096                         // edges per fill block
#define PCAP 2560                        // padded bucket capacity (mean 2048, sd 45)
#define SCCH ((NB + 63) / 64)            // 7: scan chunk per lane
#define K1B ((N_NODES + 63) / 64)        // 782 GEMM blocks
#define K2_BLOCKS 32
#define GRID (K1B + FB)                  // 978 blocks; co-resident:
                                         // LDS 32KB -> 5/CU, VGPR<=128 -> 4/CU
                                         // => 1024 slots >= 978 (margin 46)
#define NPART 64                         // BN partial-sum arrays
#define SROWS ((N_NODES + GRID - 1) / GRID)   // 52 rows/block in stats/apply

typedef __attribute__((ext_vector_type(8))) short short8;
typedef __attribute__((ext_vector_type(8))) unsigned short us8;
typedef __attribute__((ext_vector_type(4))) float f32x4;

// ---- monotonic float<->uint encoding for atomicMax on floats ----
__device__ __forceinline__ unsigned enc_max(float f) {
    unsigned u = __float_as_uint(f);
    return ((int)u >= 0) ? (u | 0x80000000u) : ~u;
}
__device__ __forceinline__ float dec_max(unsigned u) {
    return (u & 0x80000000u) ? __uint_as_float(u ^ 0x80000000u)
                             : __uint_as_float(~u);
}

__device__ __forceinline__ float leaky(float v) {
    return v > 0.f ? v : LEAKY * v;
}

// fp32 -> bf16 (round-to-nearest-even), finite inputs
__device__ __forceinline__ unsigned short f2bf(float f) {
    unsigned u = __float_as_uint(f);
    u = (u + 0x7FFFu + ((u >> 16) & 1u)) >> 16;
    return (unsigned short)u;
}
__device__ __forceinline__ float bf2f(unsigned short u) {
    return __uint_as_float(((unsigned)u) << 16);
}

// ============================================================
// Manual grid barrier (normal launch; graph-capture safe).
// Arrive: device-scope acq_rel RMW (publishes prior stores via L2 wb).
// Spin: device-scope ACQUIRE *loads* (coherent, no RMW serialization;
// L3 serves many pollers). Trailing acquire semantics invalidate the
// CU's stale L1/L2 lines before phase N+1 reads other-XCD data.
// Safe only because all GRID blocks are co-resident (see GRID above).
// ============================================================
__device__ __forceinline__ void gridbar(int* ctr) {
    __syncthreads();
    if (threadIdx.x == 0) {
        __hip_atomic_fetch_add(ctr, 1, __ATOMIC_ACQ_REL,
                               __HIP_MEMORY_SCOPE_AGENT);
        while (__hip_atomic_load(ctr, __ATOMIC_ACQUIRE,
                                 __HIP_MEMORY_SCOPE_AGENT) < GRID)
            __builtin_amdgcn_s_sleep(8);
    }
    __syncthreads();
}

// ============================================================
// MEGA kernel: 6 phases, 5 in-kernel grid barriers, one dispatch.
//  1: GEMM (blocks 0..781) || edge bucket-fill (blocks 782..977)
//  2: bucket fine-sort (0..390) || per-head node max (391..422)
//  3: pull aggregation (grid-stride, barrier-free per block)
//  4: BN stats -> NPART partials
//  5: collapse partials -> scale/shift (block 0)
//  6: BN apply -> out
// Replaces 6 dispatches (5 gaps ~7-8us each, R1->R3 calibration).
// ============================================================
struct FillSh { int est[FCH]; int hist[NB]; int rbase[NB]; };  // 19.5 KB
struct SortSh {
    int ebl[PCAP]; int csc[NB + 1];
    int deg_l[128]; int excl_l[128]; int cur_l[128];
    int wtot;
};                                                             // ~13.3 KB
struct StatSh { float lsum[HD]; float lsq[HD]; };              // 1 KB
union MegaSh { unsigned short Wl[32 * 64 * 8]; FillSh fl; SortSh so;
               StatSh st; float red[4][8]; };                  // 32 KB

__global__ __launch_bounds__(256, 4) void mega(
    const float* __restrict__ x, const float* __restrict__ W,
    const float* __restrict__ a_src, const float* __restrict__ a_tgt,
    const int* __restrict__ src, const int* __restrict__ tgt,
    int* __restrict__ bcur, int* __restrict__ ebkt,
    unsigned short* __restrict__ hb, float* __restrict__ s,
    float* __restrict__ t, int* __restrict__ rowptr,
    unsigned short* __restrict__ esrc,
    unsigned* __restrict__ smax, unsigned* __restrict__ tmax,
    unsigned short* __restrict__ outpb,
    float* __restrict__ bnp_sum, float* __restrict__ bnp_sq,
    float* __restrict__ gsc, float* __restrict__ gsh,
    const float* __restrict__ gamma, const float* __restrict__ beta,
    float* __restrict__ out, int* __restrict__ bars)
{
    __shared__ MegaSh sh;
    const int tid  = threadIdx.x;
    const int bid  = blockIdx.x;
    const int lane = tid & 63, wv = tid >> 6;

    // ================= phase 1: GEMM || fill =================
    if (bid >= K1B) {
        int* est   = sh.fl.est;
        int* hist  = sh.fl.hist;
        int* rbase = sh.fl.rbase;
        int beg = (bid - K1B) * FCH;
        int cnt = min(beg + FCH, E_EDGES) - beg;
        for (int i = tid; i < NB; i += 256) hist[i] = 0;
        __syncthreads();
        for (int j = tid; j < cnt; j += 256) {
            int sv = src[beg + j], tv = tgt[beg + j];   // both < 65536
            est[j] = sv | (tv << 16);
            atomicAdd(&hist[tv >> BSH], 1);
        }
        __syncthreads();
        for (int i = tid; i < NB; i += 256) {
            int c = hist[i];
            if (c) {
                int r = atomicAdd(&bcur[i], c);
                rbase[i] = i * PCAP + min(r, PCAP);
            }
        }
        __syncthreads();
        for (int i = tid; i < NB; i += 256) hist[i] = 0;  // reuse as cursor
        __syncthreads();
        for (int j = tid; j < cnt; j += 256) {
            int p  = est[j];
            int tv = (int)((unsigned)p >> 16);
            int b  = tv >> BSH;
            int off = atomicAdd(&hist[b], 1);
            int idx = rbase[b] + off;
            if (idx < (b + 1) * PCAP)             // overflow guard (never hits)
                ebkt[idx] = (p & 0xFFFF) | ((tv & 127) << 16);
        }
    } else {
        // W staged into LDS pre-swizzled into B-fragment layout (32 KB).
        unsigned short* Wl = sh.Wl;
        for (int idx = tid; idx < 2048; idx += 256) {
            int l  = idx & 63;
            int f  = idx >> 6;
            int nt = f >> 2, kc = f & 3;
            int kbase = kc * 32 + ((l >> 4) << 3);
            int col   = nt * 16 + (l & 15);
            unsigned short* dst = &Wl[idx * 8];
#pragma unroll
            for (int j = 0; j < 8; j++)
                dst[j] = f2bf(W[(kbase + j) * HD + col]);
        }
        __syncthreads();

        const int quad = lane >> 4, rl = lane & 15;
        const int row0 = bid * 64 + wv * 16;
        const int crow = min(row0 + rl, N_NODES - 1);

        short8 a[4];
        const float* xp = x + (size_t)crow * IN_DIM + quad * 8;
#pragma unroll
        for (int kc = 0; kc < 4; kc++) {
            float4 v0 = *(const float4*)(xp + kc * 32);
            float4 v1 = *(const float4*)(xp + kc * 32 + 4);
            short8 av;
            av[0] = (short)f2bf(v0.x); av[1] = (short)f2bf(v0.y);
            av[2] = (short)f2bf(v0.z); av[3] = (short)f2bf(v0.w);
            av[4] = (short)f2bf(v1.x); av[5] = (short)f2bf(v1.y);
            av[6] = (short)f2bf(v1.z); av[7] = (short)f2bf(v1.w);
            a[kc] = av;
        }

        float asv[8], atv[8];
#pragma unroll
        for (int nt = 0; nt < 8; nt++) {
            asv[nt] = a_src[nt * 16 + rl];
            atv[nt] = a_tgt[nt * 16 + rl];
        }

        float ps[4][4], pt[4][4];   // [head][r]
#pragma unroll
        for (int hh = 0; hh < 4; hh++)
#pragma unroll
            for (int r = 0; r < 4; r++) { ps[hh][r] = 0.f; pt[hh][r] = 0.f; }

#pragma unroll
        for (int nt = 0; nt < 8; nt++) {
            f32x4 acc = {0.f, 0.f, 0.f, 0.f};
#pragma unroll
            for (int kc = 0; kc < 4; kc++) {
                short8 b = *(const short8*)&Wl[((nt * 4 + kc) * 64 + lane) * 8];
                acc = __builtin_amdgcn_mfma_f32_16x16x32_bf16(a[kc], b, acc, 0, 0, 0);
            }
            const int ocol = nt * 16 + rl;
            const int hh   = nt >> 1;
#pragma unroll
            for (int r = 0; r < 4; r++) {
                int orow = row0 + quad * 4 + r;
                if (orow < N_NODES)
                    hb[(size_t)orow * HD + ocol] = f2bf(acc[r]);
                ps[hh][r] = fmaf(acc[r], asv[nt], ps[hh][r]);
                pt[hh][r] = fmaf(acc[r], atv[nt], pt[hh][r]);
            }
        }

#pragma unroll
        for (int m = 1; m <= 8; m <<= 1) {
#pragma unroll
            for (int hh = 0; hh < 4; hh++)
#pragma unroll
                for (int r = 0; r < 4; r++) {
                    ps[hh][r] += __shfl_xor(ps[hh][r], m, 64);
                    pt[hh][r] += __shfl_xor(pt[hh][r], m, 64);
                }
        }
        if (rl == 0) {
#pragma unroll
            for (int r = 0; r < 4; r++) {
                int orow = row0 + quad * 4 + r;
                if (orow < N_NODES) {
#pragma unroll
                    for (int hh = 0; hh < 4; hh++) {
                        s[orow * HEADS + hh] = ps[hh][r];
                        t[orow * HEADS + hh] = pt[hh][r];
                    }
                }
            }
        }
    }

    gridbar(&bars[0]);

    // ================= phase 2: sort || max =================
    if (bid < NB) {
        int b = bid;
        int* ebl    = sh.so.ebl;
        int* csc    = sh.so.csc;
        int* deg_l  = sh.so.deg_l;
        int* excl_l = sh.so.excl_l;
        int* cur_l  = sh.so.cur_l;

        for (int i = tid; i < NB; i += 256) csc[i] = min(bcur[i], PCAP);
        if (tid < 128) { deg_l[tid] = 0; cur_l[tid] = 0; }
        __syncthreads();
        // wave-0 chunked exclusive scan of csc[0..NB)
        if (tid < 64) {
            int cb = tid * SCCH;
            int loc[SCCH];
            int sum = 0;
#pragma unroll
            for (int k = 0; k < SCCH; k++) {
                int idx = cb + k;
                int v = (idx < NB) ? csc[idx] : 0;
                loc[k] = sum; sum += v;
            }
            int ss = sum;
#pragma unroll
            for (int off = 1; off < 64; off <<= 1) {
                int u = __shfl_up(ss, off, 64);
                if (tid >= off) ss += u;
            }
            int excl = ss - sum;
#pragma unroll
            for (int k = 0; k < SCCH; k++) {
                int idx = cb + k;
                if (idx < NB) csc[idx] = excl + loc[k];
            }
            if (tid == 63) {
                csc[NB] = excl + sum;             // == E_EDGES
                if (b == 0) rowptr[N_NODES] = excl + sum;
            }
        }
        __syncthreads();
        int base_in = b * PCAP;
        int base    = csc[b];
        int cnt     = csc[b + 1] - base;          // <= PCAP

        for (int j = tid; j < cnt; j += 256) {
            int p = ebkt[base_in + j];
            ebl[j] = p;
            atomicAdd(&deg_l[p >> 16], 1);
        }
        __syncthreads();

        int v = (tid < 128) ? deg_l[tid] : 0;
        int sv2 = v;
#pragma unroll
        for (int off = 1; off < 64; off <<= 1) {
            int u = __shfl_up(sv2, off, 64);
            if (lane >= off) sv2 += u;
        }
        if (tid == 63) sh.so.wtot = sv2;
        __syncthreads();
        if (tid < 128) {
            int ex = sv2 - v + ((wv == 1) ? sh.so.wtot : 0);
            excl_l[tid] = ex;
            int node = (b << BSH) + tid;
            if (node < N_NODES) rowptr[node] = base + ex;
        }
        __syncthreads();
        for (int j = tid; j < cnt; j += 256) {
            int p  = ebl[j];
            int tl = p >> 16;
            int off = atomicAdd(&cur_l[tl], 1);
            esrc[base + excl_l[tl] + off] = (unsigned short)(p & 0xFFFF);
        }
    } else if (bid < NB + K2_BLOCKS) {
        int bI = bid - NB;
        float sm0 = -INFINITY, sm1 = -INFINITY, sm2 = -INFINITY, sm3 = -INFINITY;
        float tm0 = -INFINITY, tm1 = -INFINITY, tm2 = -INFINITY, tm3 = -INFINITY;
        for (int n = bI * 256 + tid; n < N_NODES; n += K2_BLOCKS * 256) {
            float4 s4 = ((const float4*)s)[n];
            float4 t4 = ((const float4*)t)[n];
            sm0 = fmaxf(sm0, s4.x); sm1 = fmaxf(sm1, s4.y);
            sm2 = fmaxf(sm2, s4.z); sm3 = fmaxf(sm3, s4.w);
            tm0 = fmaxf(tm0, t4.x); tm1 = fmaxf(tm1, t4.y);
            tm2 = fmaxf(tm2, t4.z); tm3 = fmaxf(tm3, t4.w);
        }
#pragma unroll
        for (int m = 32; m >= 1; m >>= 1) {
            sm0 = fmaxf(sm0, __shfl_xor(sm0, m, 64));
            sm1 = fmaxf(sm1, __shfl_xor(sm1, m, 64));
            sm2 = fmaxf(sm2, __shfl_xor(sm2, m, 64));
            sm3 = fmaxf(sm3, __shfl_xor(sm3, m, 64));
            tm0 = fmaxf(tm0, __shfl_xor(tm0, m, 64));
            tm1 = fmaxf(tm1, __shfl_xor(tm1, m, 64));
            tm2 = fmaxf(tm2, __shfl_xor(tm2, m, 64));
            tm3 = fmaxf(tm3, __shfl_xor(tm3, m, 64));
        }
        if (lane == 0) {
            sh.red[wv][0] = sm0; sh.red[wv][1] = sm1;
            sh.red[wv][2] = sm2; sh.red[wv][3] = sm3;
            sh.red[wv][4] = tm0; sh.red[wv][5] = tm1;
            sh.red[wv][6] = tm2; sh.red[wv][7] = tm3;
        }
        __syncthreads();
        if (tid < 8) {
            float v = fmaxf(fmaxf(sh.red[0][tid], sh.red[1][tid]),
                            fmaxf(sh.red[2][tid], sh.red[3][tid]));
            unsigned* dst = (tid < 4) ? &smax[tid] : &tmax[tid - 4];
            atomicMax(dst, enc_max(v));
        }
    }

    gridbar(&bars[1]);

    // ================= phase 3: pull (grid-stride) =================
    for (int g = bid * 256 + tid; g < N_NODES * 16; g += GRID * 256) {
        int node = g >> 4;
        int lane16 = g & 15;
        int head = lane16 >> 2;               // 4 lanes per head, 8 ch each
        int beg = rowptr[node];
        int end = rowptr[node + 1];
        float mx = leaky(dec_max(smax[head]) + dec_max(tmax[head]));
        float tv = t[node * HEADS + head];

        float p0 = 0.f, p1 = 0.f, p2 = 0.f, p3 = 0.f;
        float p4 = 0.f, p5 = 0.f, p6 = 0.f, p7 = 0.f, psum = 0.f;
        float q0 = 0.f, q1 = 0.f, q2 = 0.f, q3 = 0.f;
        float q4 = 0.f, q5 = 0.f, q6 = 0.f, q7 = 0.f, qsum = 0.f;
        const unsigned short* hbase = hb + lane16 * 8;

        for (int j = beg; j < end; j += 8) {
            int lim = end - j;                // >= 1
            int si[8];
#pragma unroll
            for (int u = 0; u < 8; u++) {
                int uu = (u < lim) ? u : (lim - 1);
                si[u] = __builtin_nontemporal_load(&esrc[j + uu]);
            }
            float sv[8];
            us8 hv[8];
#pragma unroll
            for (int u = 0; u < 8; u++) {
                sv[u] = s[si[u] * HEADS + head];
                hv[u] = *(const us8*)(hbase + (size_t)si[u] * HD);
            }
            float al[8];
#pragma unroll
            for (int u = 0; u < 8; u++) {
                float a = __expf(leaky(sv[u] + tv) - mx);
                al[u] = (u < lim) ? a : 0.f;
            }
#pragma unroll
            for (int u = 0; u < 8; u += 2) {
                float a0 = al[u], a1 = al[u + 1];
                p0 = fmaf(a0, bf2f(hv[u][0]), p0);  q0 = fmaf(a1, bf2f(hv[u+1][0]), q0);
                p1 = fmaf(a0, bf2f(hv[u][1]), p1);  q1 = fmaf(a1, bf2f(hv[u+1][1]), q1);
                p2 = fmaf(a0, bf2f(hv[u][2]), p2);  q2 = fmaf(a1, bf2f(hv[u+1][2]), q2);
                p3 = fmaf(a0, bf2f(hv[u][3]), p3);  q3 = fmaf(a1, bf2f(hv[u+1][3]), q3);
                p4 = fmaf(a0, bf2f(hv[u][4]), p4);  q4 = fmaf(a1, bf2f(hv[u+1][4]), q4);
                p5 = fmaf(a0, bf2f(hv[u][5]), p5);  q5 = fmaf(a1, bf2f(hv[u+1][5]), q5);
                p6 = fmaf(a0, bf2f(hv[u][6]), p6);  q6 = fmaf(a1, bf2f(hv[u+1][6]), q6);
                p7 = fmaf(a0, bf2f(hv[u][7]), p7);  q7 = fmaf(a1, bf2f(hv[u+1][7]), q7);
                psum += a0; qsum += a1;
            }
        }

        float w = 1.0f / (psum + qsum + 1e-16f);
        us8 o;
        o[0] = f2bf((p0 + q0) * w); o[1] = f2bf((p1 + q1) * w);
        o[2] = f2bf((p2 + q2) * w); o[3] = f2bf((p3 + q3) * w);
        o[4] = f2bf((p4 + q4) * w); o[5] = f2bf((p5 + q5) * w);
        o[6] = f2bf((p6 + q6) * w); o[7] = f2bf((p7 + q7) * w);
        *(us8*)(outpb + (size_t)node * HD + lane16 * 8) = o;
    }

    gridbar(&bars[2]);

    // ================= phase 4: BN stats =================
    {
        int c8  = tid & 15;
        int grp = tid >> 4;
        if (tid < HD) { sh.st.lsum[tid] = 0.f; sh.st.lsq[tid] = 0.f; }
        __syncthreads();
        int rbeg = bid * SROWS;
        int rend = min(rbeg + SROWS, N_NODES);
        float sm[8], sq[8];
#pragma unroll
        for (int i = 0; i < 8; i++) { sm[i] = 0.f; sq[i] = 0.f; }
        for (int r = rbeg + grp; r < rend; r += 16) {
            us8 v = *(const us8*)(outpb + (size_t)r * HD + c8 * 8);
#pragma unroll
            for (int i = 0; i < 8; i++) {
                float f = bf2f(v[i]);
                sm[i] += f;
                sq[i] = fmaf(f, f, sq[i]);
            }
        }
#pragma unroll
        for (int i = 0; i < 8; i++) {
            atomicAdd(&sh.st.lsum[c8 * 8 + i], sm[i]);
            atomicAdd(&sh.st.lsq[c8 * 8 + i], sq[i]);
        }
        __syncthreads();
        if (tid < HD && rbeg < N_NODES) {
            int ps = bid & (NPART - 1);
            unsafeAtomicAdd(&bnp_sum[ps * HD + tid], sh.st.lsum[tid]);
            unsafeAtomicAdd(&bnp_sq [ps * HD + tid], sh.st.lsq[tid]);
        }
    }

    gridbar(&bars[3]);

    // ================= phase 5: collapse (block 0) =================
    if (bid == 0 && tid < HD) {
        float sm = 0.f, sq = 0.f;
#pragma unroll 4
        for (int p = 0; p < NPART; p++) {
            sm += bnp_sum[p * HD + tid];
            sq += bnp_sq [p * HD + tid];
        }
        float inv_n = 1.0f / (float)N_NODES;
        float mean = sm * inv_n;
        float var  = sq * inv_n - mean * mean;
        float sc   = gamma[tid] * rsqrtf(var + BN_EPS);
        gsc[tid] = sc;
        gsh[tid] = beta[tid] - mean * sc;
    }

    gridbar(&bars[4]);

    // ================= phase 6: BN apply =================
    {
        int c8  = tid & 15;
        int grp = tid >> 4;
        float scale[8], shift[8];
#pragma unroll
        for (int i = 0; i < 8; i++) {
            scale[i] = gsc[c8 * 8 + i];
            shift[i] = gsh[c8 * 8 + i];
        }
        int rbeg = bid * SROWS;
        int rend = min(rbeg + SROWS, N_NODES);
        for (int r = rbeg + grp; r < rend; r += 16) {
            us8 v = *(const us8*)(outpb + (size_t)r * HD + c8 * 8);
            float4 o0, o1;
            o0.x = fmaf(bf2f(v[0]), scale[0], shift[0]);
            o0.y = fmaf(bf2f(v[1]), scale[1], shift[1]);
            o0.z = fmaf(bf2f(v[2]), scale[2], shift[2]);
            o0.w = fmaf(bf2f(v[3]), scale[3], shift[3]);
            o1.x = fmaf(bf2f(v[4]), scale[4], shift[4]);
            o1.y = fmaf(bf2f(v[5]), scale[5], shift[5]);
            o1.z = fmaf(bf2f(v[6]), scale[6], shift[6]);
            o1.w = fmaf(bf2f(v[7]), scale[7], shift[7]);
            float* op = out + (size_t)r * HD + c8 * 8;
            ((float4*)op)[0] = o0;
            ((float4*)op)[1] = o1;
        }
    }
}

// ============================================================
extern "C" void kernel_launch(void* const* d_in, const int* in_sizes, int n_in,
                              void* d_out, int out_size, void* d_ws, size_t ws_size,
                              hipStream_t stream)
{
    const float* x     = (const float*)d_in[0];
    const float* W     = (const float*)d_in[1];
    const float* a_src = (const float*)d_in[2];
    const float* a_tgt = (const float*)d_in[3];
    const float* gamma = (const float*)d_in[4];
    const float* beta  = (const float*)d_in[5];
    const int*   eidx  = (const int*)d_in[6];
    const int* src = eidx;
    const int* tgt = eidx + E_EDGES;
    float* out = (float*)d_out;

    // workspace layout
    unsigned short* hb    = (unsigned short*)d_ws;          // 6.4M ushort
    float*          s     = (float*)d_ws + 3200000;         // 200K float
    float*          t     = s + (size_t)N_NODES * HEADS;    // 200K float
    unsigned short* outpb = (unsigned short*)(t + (size_t)N_NODES * HEADS); // 6.4M us
    int*            ebkt  = (int*)outpb;                    // NB*PCAP=1.0M int (aliases outpb)
    unsigned short* esrc  = outpb + 6400000;                // 800K ushort
    int*            rowptr= (int*)(esrc + E_EDGES);         // 50,001 int
    // ---- zero-init region (single memset) ----
    int*      bcur  = rowptr + N_NODES + 1;                 // 392
    unsigned* smax  = (unsigned*)(bcur + 392);              // 4
    unsigned* tmax  = smax + 4;                             // 4
    int*      bars  = (int*)(tmax + 4);                     // 8 (5 used)
    float*    bnp_sum = (float*)(bars + 8);                 // 64*128
    float*    bnp_sq  = bnp_sum + NPART * HD;               // 64*128
    size_t zero_bytes = (392 + 8 + 8 + 2 * NPART * HD) * 4; // ~67 KB
    // ---- not zeroed ----
    float*    gsc = bnp_sq + NPART * HD;                    // 128
    float*    gsh = gsc + HD;                               // 128
    hipMemsetAsync(bcur, 0, zero_bytes, stream);

    mega<<<GRID, 256, 0, stream>>>(x, W, a_src, a_tgt, src, tgt,
                                   bcur, ebkt, hb, s, t, rowptr, esrc,
                                   smax, tmax, outpb, bnp_sum, bnp_sq,
                                   gsc, gsh, gamma, beta, out, bars);
}

// Round 8
// 265.949 us; speedup vs baseline: 3.2244x; 3.2244x over previous
//
#include <hip/hip_runtime.h>
#include <math.h>

#define N_NODES 50000
#define E_EDGES 800000
#define IN_DIM 128
#define HEADS 4
#define OUT_DIM 32
#define HD 128          // HEADS*OUT_DIM
#define LEAKY 0.4f
#define BN_EPS 1e-5f

// bucketed counting sort params: bucket = tgt >> 7 (128 targets/bucket)
#define BSH 7
#define NB ((N_NODES + 127) >> BSH)     // 391
#define FB 196                           // fill block count
#define FCH 4096                         // edges per fill block
#define PCAP 2560                        // padded bucket capacity (mean 2048, sd 45)
#define SCCH ((NB + 63) / 64)            // 7: scan chunk per lane
#define K1B ((N_NODES + 63) / 64)        // 782 GEMM blocks
#define K2_BLOCKS 32
#define NPART 64                         // BN partial-sum arrays

typedef __attribute__((ext_vector_type(8))) short short8;
typedef __attribute__((ext_vector_type(8))) unsigned short us8;
typedef __attribute__((ext_vector_type(4))) float f32x4;

// ---- monotonic float<->uint encoding for atomicMax on floats ----
__device__ __forceinline__ unsigned enc_max(float f) {
    unsigned u = __float_as_uint(f);
    return ((int)u >= 0) ? (u | 0x80000000u) : ~u;
}
__device__ __forceinline__ float dec_max(unsigned u) {
    return (u & 0x80000000u) ? __uint_as_float(u ^ 0x80000000u)
                             : __uint_as_float(~u);
}

__device__ __forceinline__ float leaky(float v) {
    return v > 0.f ? v : LEAKY * v;
}

// fp32 -> bf16 (round-to-nearest-even), finite inputs
__device__ __forceinline__ unsigned short f2bf(float f) {
    unsigned u = __float_as_uint(f);
    u = (u + 0x7FFFu + ((u >> 16) & 1u)) >> 16;
    return (unsigned short)u;
}
__device__ __forceinline__ float bf2f(unsigned short u) {
    return __uint_as_float(((unsigned)u) << 16);
}

// ============================================================
// F1: fused GEMM (blocks 0..K1B-1) || edge bucketing (blocks K1B..).
// Disjoint inputs; fusion forces concurrent execution (R3: worth
// ~17-21us vs serial dispatches). Simple single-pass fill (R5's LDS
// pre-sort was null). R6/R7 lesson: cooperative/spin grid barriers are
// not viable here (poll storm ~138us/barrier) -- keep separate
// dispatches for true dependencies.
// ============================================================
struct FillSh { int est[FCH]; int hist[NB]; int rbase[NB]; };  // 19.5 KB
union F1Sh { unsigned short Wl[32 * 64 * 8]; FillSh fl; };     // 32 KB

__global__ __launch_bounds__(256) void f1_gemm_fill(
    const float* __restrict__ x, const float* __restrict__ W,
    const float* __restrict__ a_src, const float* __restrict__ a_tgt,
    const int* __restrict__ src, const int* __restrict__ tgt,
    int* __restrict__ bcur, int* __restrict__ ebkt,
    unsigned short* __restrict__ hb, float* __restrict__ s,
    float* __restrict__ t)
{
    __shared__ F1Sh sh;
    const int tid = threadIdx.x;

    if (blockIdx.x >= K1B) {
        // ---------------- fill path ----------------
        int* est   = sh.fl.est;
        int* hist  = sh.fl.hist;
        int* rbase = sh.fl.rbase;
        int beg = (blockIdx.x - K1B) * FCH;
        int cnt = min(beg + FCH, E_EDGES) - beg;
        for (int i = tid; i < NB; i += 256) hist[i] = 0;
        __syncthreads();
        for (int j = tid; j < cnt; j += 256) {
            int sv = src[beg + j], tv = tgt[beg + j];   // both < 65536
            est[j] = sv | (tv << 16);
            atomicAdd(&hist[tv >> BSH], 1);
        }
        __syncthreads();
        for (int i = tid; i < NB; i += 256) {
            int c = hist[i];
            if (c) {
                int r = atomicAdd(&bcur[i], c);
                rbase[i] = i * PCAP + min(r, PCAP);
            }
        }
        __syncthreads();
        for (int i = tid; i < NB; i += 256) hist[i] = 0;  // reuse as cursor
        __syncthreads();
        for (int j = tid; j < cnt; j += 256) {
            int p  = est[j];
            int tv = (int)((unsigned)p >> 16);
            int b  = tv >> BSH;
            int off = atomicAdd(&hist[b], 1);
            int idx = rbase[b] + off;
            if (idx < (b + 1) * PCAP)             // overflow guard (never hits)
                ebkt[idx] = (p & 0xFFFF) | ((tv & 127) << 16);
        }
        return;
    }

    // ---------------- GEMM path ----------------
    // W staged into LDS pre-swizzled into B-fragment layout (32 KB).
    unsigned short* Wl = sh.Wl;
    for (int idx = tid; idx < 2048; idx += 256) {
        int l  = idx & 63;
        int f  = idx >> 6;
        int nt = f >> 2, kc = f & 3;
        int kbase = kc * 32 + ((l >> 4) << 3);
        int col   = nt * 16 + (l & 15);
        unsigned short* dst = &Wl[idx * 8];
#pragma unroll
        for (int j = 0; j < 8; j++)
            dst[j] = f2bf(W[(kbase + j) * HD + col]);
    }
    __syncthreads();

    const int wave = tid >> 6, lane = tid & 63;
    const int quad = lane >> 4, rl = lane & 15;
    const int row0 = blockIdx.x * 64 + wave * 16;
    const int crow = min(row0 + rl, N_NODES - 1);

    short8 a[4];
    const float* xp = x + (size_t)crow * IN_DIM + quad * 8;
#pragma unroll
    for (int kc = 0; kc < 4; kc++) {
        float4 v0 = *(const float4*)(xp + kc * 32);
        float4 v1 = *(const float4*)(xp + kc * 32 + 4);
        short8 av;
        av[0] = (short)f2bf(v0.x); av[1] = (short)f2bf(v0.y);
        av[2] = (short)f2bf(v0.z); av[3] = (short)f2bf(v0.w);
        av[4] = (short)f2bf(v1.x); av[5] = (short)f2bf(v1.y);
        av[6] = (short)f2bf(v1.z); av[7] = (short)f2bf(v1.w);
        a[kc] = av;
    }

    float asv[8], atv[8];
#pragma unroll
    for (int nt = 0; nt < 8; nt++) {
        asv[nt] = a_src[nt * 16 + rl];
        atv[nt] = a_tgt[nt * 16 + rl];
    }

    float ps[4][4], pt[4][4];   // [head][r]
#pragma unroll
    for (int hh = 0; hh < 4; hh++)
#pragma unroll
        for (int r = 0; r < 4; r++) { ps[hh][r] = 0.f; pt[hh][r] = 0.f; }

#pragma unroll
    for (int nt = 0; nt < 8; nt++) {
        f32x4 acc = {0.f, 0.f, 0.f, 0.f};
#pragma unroll
        for (int kc = 0; kc < 4; kc++) {
            short8 b = *(const short8*)&Wl[((nt * 4 + kc) * 64 + lane) * 8];
            acc = __builtin_amdgcn_mfma_f32_16x16x32_bf16(a[kc], b, acc, 0, 0, 0);
        }
        const int ocol = nt * 16 + rl;
        const int hh   = nt >> 1;
#pragma unroll
        for (int r = 0; r < 4; r++) {
            int orow = row0 + quad * 4 + r;
            if (orow < N_NODES)
                hb[(size_t)orow * HD + ocol] = f2bf(acc[r]);
            ps[hh][r] = fmaf(acc[r], asv[nt], ps[hh][r]);
            pt[hh][r] = fmaf(acc[r], atv[nt], pt[hh][r]);
        }
    }

#pragma unroll
    for (int m = 1; m <= 8; m <<= 1) {
#pragma unroll
        for (int hh = 0; hh < 4; hh++)
#pragma unroll
            for (int r = 0; r < 4; r++) {
                ps[hh][r] += __shfl_xor(ps[hh][r], m, 64);
                pt[hh][r] += __shfl_xor(pt[hh][r], m, 64);
            }
    }
    if (rl == 0) {
#pragma unroll
        for (int r = 0; r < 4; r++) {
            int orow = row0 + quad * 4 + r;
            if (orow < N_NODES) {
#pragma unroll
                for (int hh = 0; hh < 4; hh++) {
                    s[orow * HEADS + hh] = ps[hh][r];
                    t[orow * HEADS + hh] = pt[hh][r];
                }
            }
        }
    }
}

// ============================================================
// F2: fused bucket fine-sort (blocks 0..NB-1) || per-head node max
// (blocks NB..NB+K2_BLOCKS-1). Independent inputs, forced overlap.
// ============================================================
struct SortSh {
    int ebl[PCAP]; int csc[NB + 1];
    int deg_l[128]; int excl_l[128]; int cur_l[128];
    int wtot;
};                                                             // ~13.3 KB
union F2Sh { SortSh so; float red[4][8]; };

__global__ __launch_bounds__(256) void f2_sort_max(
    const int* __restrict__ bcur, const int* __restrict__ ebkt,
    int* __restrict__ rowptr, unsigned short* __restrict__ esrc,
    const float* __restrict__ s, const float* __restrict__ t,
    unsigned* __restrict__ smax, unsigned* __restrict__ tmax)
{
    __shared__ F2Sh sh;
    int tid  = threadIdx.x;
    int lane = tid & 63, wv = tid >> 6;

    if (blockIdx.x >= NB) {
        // ---------------- node-max path ----------------
        int bI = blockIdx.x - NB;
        float sm0 = -INFINITY, sm1 = -INFINITY, sm2 = -INFINITY, sm3 = -INFINITY;
        float tm0 = -INFINITY, tm1 = -INFINITY, tm2 = -INFINITY, tm3 = -INFINITY;
        for (int n = bI * 256 + tid; n < N_NODES; n += K2_BLOCKS * 256) {
            float4 s4 = ((const float4*)s)[n];
            float4 t4 = ((const float4*)t)[n];
            sm0 = fmaxf(sm0, s4.x); sm1 = fmaxf(sm1, s4.y);
            sm2 = fmaxf(sm2, s4.z); sm3 = fmaxf(sm3, s4.w);
            tm0 = fmaxf(tm0, t4.x); tm1 = fmaxf(tm1, t4.y);
            tm2 = fmaxf(tm2, t4.z); tm3 = fmaxf(tm3, t4.w);
        }
#pragma unroll
        for (int m = 32; m >= 1; m >>= 1) {
            sm0 = fmaxf(sm0, __shfl_xor(sm0, m, 64));
            sm1 = fmaxf(sm1, __shfl_xor(sm1, m, 64));
            sm2 = fmaxf(sm2, __shfl_xor(sm2, m, 64));
            sm3 = fmaxf(sm3, __shfl_xor(sm3, m, 64));
            tm0 = fmaxf(tm0, __shfl_xor(tm0, m, 64));
            tm1 = fmaxf(tm1, __shfl_xor(tm1, m, 64));
            tm2 = fmaxf(tm2, __shfl_xor(tm2, m, 64));
            tm3 = fmaxf(tm3, __shfl_xor(tm3, m, 64));
        }
        if (lane == 0) {
            sh.red[wv][0] = sm0; sh.red[wv][1] = sm1;
            sh.red[wv][2] = sm2; sh.red[wv][3] = sm3;
            sh.red[wv][4] = tm0; sh.red[wv][5] = tm1;
            sh.red[wv][6] = tm2; sh.red[wv][7] = tm3;
        }
        __syncthreads();
        if (tid < 8) {
            float v = fmaxf(fmaxf(sh.red[0][tid], sh.red[1][tid]),
                            fmaxf(sh.red[2][tid], sh.red[3][tid]));
            unsigned* dst = (tid < 4) ? &smax[tid] : &tmax[tid - 4];
            atomicMax(dst, enc_max(v));
        }
        return;
    }

    // ---------------- bucket fine-sort path ----------------
    int b = blockIdx.x;
    int* ebl    = sh.so.ebl;
    int* csc    = sh.so.csc;
    int* deg_l  = sh.so.deg_l;
    int* excl_l = sh.so.excl_l;
    int* cur_l  = sh.so.cur_l;

    for (int i = tid; i < NB; i += 256) csc[i] = min(bcur[i], PCAP);
    if (tid < 128) { deg_l[tid] = 0; cur_l[tid] = 0; }
    __syncthreads();
    // wave-0 chunked exclusive scan of csc[0..NB)
    if (tid < 64) {
        int cb = tid * SCCH;
        int loc[SCCH];
        int sum = 0;
#pragma unroll
        for (int k = 0; k < SCCH; k++) {
            int idx = cb + k;
            int v = (idx < NB) ? csc[idx] : 0;
            loc[k] = sum; sum += v;
        }
        int ss = sum;
#pragma unroll
        for (int off = 1; off < 64; off <<= 1) {
            int u = __shfl_up(ss, off, 64);
            if (tid >= off) ss += u;
        }
        int excl = ss - sum;
#pragma unroll
        for (int k = 0; k < SCCH; k++) {
            int idx = cb + k;
            if (idx < NB) csc[idx] = excl + loc[k];
        }
        if (tid == 63) {
            csc[NB] = excl + sum;             // == E_EDGES
            if (b == 0) rowptr[N_NODES] = excl + sum;
        }
    }
    __syncthreads();
    int base_in = b * PCAP;
    int base    = csc[b];
    int cnt     = csc[b + 1] - base;          // <= PCAP

    // stage + per-target degree histogram
    for (int j = tid; j < cnt; j += 256) {
        int p = ebkt[base_in + j];
        ebl[j] = p;
        atomicAdd(&deg_l[p >> 16], 1);
    }
    __syncthreads();

    // exclusive scan of 128 target degrees
    int v = (tid < 128) ? deg_l[tid] : 0;
    int sv2 = v;
#pragma unroll
    for (int off = 1; off < 64; off <<= 1) {
        int u = __shfl_up(sv2, off, 64);
        if (lane >= off) sv2 += u;
    }
    if (tid == 63) sh.so.wtot = sv2;
    __syncthreads();
    if (tid < 128) {
        int ex = sv2 - v + ((wv == 1) ? sh.so.wtot : 0);
        excl_l[tid] = ex;
        int node = (b << BSH) + tid;
        if (node < N_NODES) rowptr[node] = base + ex;
    }
    __syncthreads();
    for (int j = tid; j < cnt; j += 256) {
        int p  = ebl[j];
        int tl = p >> 16;
        int off = atomicAdd(&cur_l[tl], 1);
        esrc[base + excl_l[tl] + off] = (unsigned short)(p & 0xFFFF);
    }
}

// ============================================================
// K4: pull aggregation + fused BN stats at WAVE granularity.
// 16 lanes per node, 8 bf16 ch each; barrier-free per block (R2
// lesson: block-wide sync in this latency-bound gather loop is a 2x
// regression; wave shuffles have no such coupling). A 64-lane wave =
// 4 nodes x 16 channel-octets: two shfl_xor steps (masks 16,32) sum
// the 4 nodes' bf16-rounded outputs in-register, low 16 lanes emit
// one unsafeAtomicAdd pair per channel into NPART partial arrays.
// Eliminates the k5 stats pass (12.8MB re-read + one dispatch).
// Grid is exactly N_NODES*16/256 = 3125 blocks: no range guard.
// ============================================================
__global__ __launch_bounds__(256) void k4_pull(
    const int* __restrict__ rowptr, const unsigned short* __restrict__ esrc,
    const float* __restrict__ s, const float* __restrict__ t,
    const unsigned* __restrict__ smax, const unsigned* __restrict__ tmax,
    const unsigned short* __restrict__ hb, unsigned short* __restrict__ outpb,
    float* __restrict__ bnp_sum, float* __restrict__ bnp_sq)
{
    int g = blockIdx.x * 256 + threadIdx.x;
    int node = g >> 4;
    int lane = g & 15;
    int head = lane >> 2;                 // 4 lanes per head, 8 ch each
    int beg = rowptr[node];
    int end = rowptr[node + 1];
    float mx = leaky(dec_max(smax[head]) + dec_max(tmax[head]));
    float tv = t[node * HEADS + head];

    float p0 = 0.f, p1 = 0.f, p2 = 0.f, p3 = 0.f;
    float p4 = 0.f, p5 = 0.f, p6 = 0.f, p7 = 0.f, psum = 0.f;
    float q0 = 0.f, q1 = 0.f, q2 = 0.f, q3 = 0.f;
    float q4 = 0.f, q5 = 0.f, q6 = 0.f, q7 = 0.f, qsum = 0.f;
    const unsigned short* hbase = hb + lane * 8;

    for (int j = beg; j < end; j += 8) {
        int lim = end - j;                // >= 1
        int si[8];
#pragma unroll
        for (int u = 0; u < 8; u++) {
            int uu = (u < lim) ? u : (lim - 1);
            si[u] = __builtin_nontemporal_load(&esrc[j + uu]);
        }
        float sv[8];
        us8 hv[8];
#pragma unroll
        for (int u = 0; u < 8; u++) {
            sv[u] = s[si[u] * HEADS + head];
            hv[u] = *(const us8*)(hbase + (size_t)si[u] * HD);
        }
        float al[8];
#pragma unroll
        for (int u = 0; u < 8; u++) {
            float a = __expf(leaky(sv[u] + tv) - mx);
            al[u] = (u < lim) ? a : 0.f;
        }
#pragma unroll
        for (int u = 0; u < 8; u += 2) {
            float a0 = al[u], a1 = al[u + 1];
            p0 = fmaf(a0, bf2f(hv[u][0]), p0);  q0 = fmaf(a1, bf2f(hv[u+1][0]), q0);
            p1 = fmaf(a0, bf2f(hv[u][1]), p1);  q1 = fmaf(a1, bf2f(hv[u+1][1]), q1);
            p2 = fmaf(a0, bf2f(hv[u][2]), p2);  q2 = fmaf(a1, bf2f(hv[u+1][2]), q2);
            p3 = fmaf(a0, bf2f(hv[u][3]), p3);  q3 = fmaf(a1, bf2f(hv[u+1][3]), q3);
            p4 = fmaf(a0, bf2f(hv[u][4]), p4);  q4 = fmaf(a1, bf2f(hv[u+1][4]), q4);
            p5 = fmaf(a0, bf2f(hv[u][5]), p5);  q5 = fmaf(a1, bf2f(hv[u+1][5]), q5);
            p6 = fmaf(a0, bf2f(hv[u][6]), p6);  q6 = fmaf(a1, bf2f(hv[u+1][6]), q6);
            p7 = fmaf(a0, bf2f(hv[u][7]), p7);  q7 = fmaf(a1, bf2f(hv[u+1][7]), q7);
            psum += a0; qsum += a1;
        }
    }

    float w = 1.0f / (psum + qsum + 1e-16f);
    us8 o;
    o[0] = f2bf((p0 + q0) * w); o[1] = f2bf((p1 + q1) * w);
    o[2] = f2bf((p2 + q2) * w); o[3] = f2bf((p3 + q3) * w);
    o[4] = f2bf((p4 + q4) * w); o[5] = f2bf((p5 + q5) * w);
    o[6] = f2bf((p6 + q6) * w); o[7] = f2bf((p7 + q7) * w);
    *(us8*)(outpb + (size_t)node * HD + lane * 8) = o;

    // ---- wave-level BN stats (no barriers, no LDS) ----
    float sm[8], sq[8];
#pragma unroll
    for (int i = 0; i < 8; i++) {
        float f = bf2f(o[i]);               // stats on bf16-rounded values
        sm[i] = f;
        sq[i] = f * f;
    }
#pragma unroll
    for (int i = 0; i < 8; i++) {
        sm[i] += __shfl_xor(sm[i], 16, 64);
        sq[i] += __shfl_xor(sq[i], 16, 64);
        sm[i] += __shfl_xor(sm[i], 32, 64);
        sq[i] += __shfl_xor(sq[i], 32, 64);
    }
    if ((threadIdx.x & 63) < 16) {
        int ps = blockIdx.x & (NPART - 1);
        float* bs = bnp_sum + ps * HD + lane * 8;
        float* bq = bnp_sq  + ps * HD + lane * 8;
#pragma unroll
        for (int i = 0; i < 8; i++) {
            unsafeAtomicAdd(&bs[i], sm[i]);
            unsafeAtomicAdd(&bq[i], sq[i]);
        }
    }
}

// ============================================================
// K6: BN apply (bf16 in, fp32 out). Prologue collapses the NPART
// partial stat arrays (L2-hot) into scale/shift in LDS (pattern
// verified in R2's f4), then applies.
// ============================================================
__global__ __launch_bounds__(256) void k6_apply(
    const unsigned short* __restrict__ outpb,
    const float* __restrict__ bnp_sum, const float* __restrict__ bnp_sq,
    const float* __restrict__ gamma, const float* __restrict__ beta,
    float* __restrict__ out)
{
    __shared__ float scs[HD], shs[HD];
    int tid = threadIdx.x;
    if (tid < HD) {
        float sm = 0.f, sq = 0.f;
#pragma unroll 4
        for (int p = 0; p < NPART; p++) {
            sm += bnp_sum[p * HD + tid];
            sq += bnp_sq [p * HD + tid];
        }
        float inv_n = 1.0f / (float)N_NODES;
        float mean = sm * inv_n;
        float var  = sq * inv_n - mean * mean;
        float sc   = gamma[tid] * rsqrtf(var + BN_EPS);
        scs[tid] = sc;
        shs[tid] = beta[tid] - mean * sc;
    }
    __syncthreads();

    int c8  = tid & 15;
    int grp = tid >> 4;
    float scale[8], shift[8];
#pragma unroll
    for (int i = 0; i < 8; i++) {
        scale[i] = scs[c8 * 8 + i];
        shift[i] = shs[c8 * 8 + i];
    }
    int base = blockIdx.x * 256;
    int end  = min(base + 256, N_NODES);
    for (int r = base + grp; r < end; r += 16) {
        us8 v = *(const us8*)(outpb + (size_t)r * HD + c8 * 8);
        float4 o0, o1;
        o0.x = fmaf(bf2f(v[0]), scale[0], shift[0]);
        o0.y = fmaf(bf2f(v[1]), scale[1], shift[1]);
        o0.z = fmaf(bf2f(v[2]), scale[2], shift[2]);
        o0.w = fmaf(bf2f(v[3]), scale[3], shift[3]);
        o1.x = fmaf(bf2f(v[4]), scale[4], shift[4]);
        o1.y = fmaf(bf2f(v[5]), scale[5], shift[5]);
        o1.z = fmaf(bf2f(v[6]), scale[6], shift[6]);
        o1.w = fmaf(bf2f(v[7]), scale[7], shift[7]);
        float* op = out + (size_t)r * HD + c8 * 8;
        ((float4*)op)[0] = o0;
        ((float4*)op)[1] = o1;
    }
}

// ============================================================
extern "C" void kernel_launch(void* const* d_in, const int* in_sizes, int n_in,
                              void* d_out, int out_size, void* d_ws, size_t ws_size,
                              hipStream_t stream)
{
    const float* x     = (const float*)d_in[0];
    const float* W     = (const float*)d_in[1];
    const float* a_src = (const float*)d_in[2];
    const float* a_tgt = (const float*)d_in[3];
    const float* gamma = (const float*)d_in[4];
    const float* beta  = (const float*)d_in[5];
    const int*   eidx  = (const int*)d_in[6];
    const int* src = eidx;
    const int* tgt = eidx + E_EDGES;
    float* out = (float*)d_out;

    // workspace layout
    unsigned short* hb    = (unsigned short*)d_ws;          // 6.4M ushort
    float*          s     = (float*)d_ws + 3200000;         // 200K float
    float*          t     = s + (size_t)N_NODES * HEADS;    // 200K float
    unsigned short* outpb = (unsigned short*)(t + (size_t)N_NODES * HEADS); // 6.4M us
    int*            ebkt  = (int*)outpb;                    // NB*PCAP=1.0M int (aliases outpb)
    unsigned short* esrc  = outpb + 6400000;                // 800K ushort
    int*            rowptr= (int*)(esrc + E_EDGES);         // 50,001 int
    // ---- zero-init region (single memset) ----
    int*      bcur  = rowptr + N_NODES + 1;                 // 392
    unsigned* smax  = (unsigned*)(bcur + 392);              // 4
    unsigned* tmax  = smax + 4;                             // 4
    float*    bnp_sum = (float*)(tmax + 4);                 // 64*128
    float*    bnp_sq  = bnp_sum + NPART * HD;               // 64*128
    size_t zero_bytes = (392 + 8 + 2 * NPART * HD) * 4;     // ~67 KB
    hipMemsetAsync(bcur, 0, zero_bytes, stream);

    // F1: GEMM || edge bucketing (independent inputs, forced overlap)
    f1_gemm_fill<<<K1B + FB, 256, 0, stream>>>(x, W, a_src, a_tgt,
                                               src, tgt, bcur, ebkt,
                                               hb, s, t);
    // F2: bucket fine-sort || per-head node max
    f2_sort_max<<<NB + K2_BLOCKS, 256, 0, stream>>>(bcur, ebkt, rowptr, esrc,
                                                    s, t, smax, tmax);
    // pull aggregation + fused wave-level BN stats
    k4_pull<<<(N_NODES * 16) / 256, 256, 0, stream>>>(
        rowptr, esrc, s, t, smax, tmax, hb, outpb, bnp_sum, bnp_sq);
    // BN apply (collapses partials in prologue)
    k6_apply<<<(N_NODES + 255) / 256, 256, 0, stream>>>(
        outpb, bnp_sum, bnp_sq, gamma, beta, out);
}

// Round 10
// 188.589 us; speedup vs baseline: 4.5471x; 1.4102x over previous
//
#include <hip/hip_runtime.h>
#include <math.h>

#define N_NODES 50000
#define E_EDGES 800000
#define IN_DIM 128
#define HEADS 4
#define OUT_DIM 32
#define HD 128          // HEADS*OUT_DIM
#define LEAKY 0.4f
#define BN_EPS 1e-5f

// bucketed counting sort params: bucket = tgt >> 7 (128 targets/bucket)
#define BSH 7
#define NB ((N_NODES + 127) >> BSH)     // 391
#define FB 196                           // fill block count
#define FCH 4096                         // edges per fill block
#define PCAP 2560                        // padded bucket capacity (mean 2048, sd 45)
#define SCCH ((NB + 63) / 64)            // 7: scan chunk per lane
#define K1B ((N_NODES + 63) / 64)        // 782 GEMM blocks
#define K2_BLOCKS 32
#define NPART 64                         // BN partial-sum arrays
#define BNB ((N_NODES + 63) / 64)        // 782 blocks for k5/k6 (64 rows each)

typedef __attribute__((ext_vector_type(8))) short short8;
typedef __attribute__((ext_vector_type(8))) unsigned short us8;
typedef __attribute__((ext_vector_type(4))) float f32x4;

// ---- monotonic float<->uint encoding for atomicMax on floats ----
__device__ __forceinline__ unsigned enc_max(float f) {
    unsigned u = __float_as_uint(f);
    return ((int)u >= 0) ? (u | 0x80000000u) : ~u;
}
__device__ __forceinline__ float dec_max(unsigned u) {
    return (u & 0x80000000u) ? __uint_as_float(u ^ 0x80000000u)
                             : __uint_as_float(~u);
}

__device__ __forceinline__ float leaky(float v) {
    return v > 0.f ? v : LEAKY * v;
}

// fp32 -> bf16 (round-to-nearest-even), finite inputs
__device__ __forceinline__ unsigned short f2bf(float f) {
    unsigned u = __float_as_uint(f);
    u = (u + 0x7FFFu + ((u >> 16) & 1u)) >> 16;
    return (unsigned short)u;
}
__device__ __forceinline__ float bf2f(unsigned short u) {
    return __uint_as_float(((unsigned)u) << 16);
}

// ============================================================
// F1: fused GEMM (blocks 0..K1B-1) || edge bucketing (blocks K1B..).
// Disjoint inputs; fusion forces concurrent execution (R3: worth
// ~17-21us vs serial dispatches). R6/R7: grid barriers not viable
// (spin poll storm); R2/R8: BN-stat fusion into the gather kernel not
// viable (LDS sync coupling / global-atomic volume). This is the
// verified-best structure (R5: 178.1us).
// ============================================================
struct FillSh { int est[FCH]; int hist[NB]; int rbase[NB]; };  // 19.5 KB
union F1Sh { unsigned short Wl[32 * 64 * 8]; FillSh fl; };     // 32 KB

__global__ __launch_bounds__(256) void f1_gemm_fill(
    const float* __restrict__ x, const float* __restrict__ W,
    const float* __restrict__ a_src, const float* __restrict__ a_tgt,
    const int* __restrict__ src, const int* __restrict__ tgt,
    int* __restrict__ bcur, int* __restrict__ ebkt,
    unsigned short* __restrict__ hb, float* __restrict__ s,
    float* __restrict__ t)
{
    __shared__ F1Sh sh;
    const int tid = threadIdx.x;

    if (blockIdx.x >= K1B) {
        // ---------------- fill path ----------------
        int* est   = sh.fl.est;
        int* hist  = sh.fl.hist;
        int* rbase = sh.fl.rbase;
        int beg = (blockIdx.x - K1B) * FCH;
        int cnt = min(beg + FCH, E_EDGES) - beg;
        for (int i = tid; i < NB; i += 256) hist[i] = 0;
        __syncthreads();
        for (int j = tid; j < cnt; j += 256) {
            int sv = src[beg + j], tv = tgt[beg + j];   // both < 65536
            est[j] = sv | (tv << 16);
            atomicAdd(&hist[tv >> BSH], 1);
        }
        __syncthreads();
        for (int i = tid; i < NB; i += 256) {
            int c = hist[i];
            if (c) {
                int r = atomicAdd(&bcur[i], c);
                rbase[i] = i * PCAP + min(r, PCAP);
            }
        }
        __syncthreads();
        for (int i = tid; i < NB; i += 256) hist[i] = 0;  // reuse as cursor
        __syncthreads();
        for (int j = tid; j < cnt; j += 256) {
            int p  = est[j];
            int tv = (int)((unsigned)p >> 16);
            int b  = tv >> BSH;
            int off = atomicAdd(&hist[b], 1);
            int idx = rbase[b] + off;
            if (idx < (b + 1) * PCAP)             // overflow guard (never hits)
                ebkt[idx] = (p & 0xFFFF) | ((tv & 127) << 16);
        }
        return;
    }

    // ---------------- GEMM path ----------------
    // W staged into LDS pre-swizzled into B-fragment layout (32 KB).
    unsigned short* Wl = sh.Wl;
    for (int idx = tid; idx < 2048; idx += 256) {
        int l  = idx & 63;
        int f  = idx >> 6;
        int nt = f >> 2, kc = f & 3;
        int kbase = kc * 32 + ((l >> 4) << 3);
        int col   = nt * 16 + (l & 15);
        unsigned short* dst = &Wl[idx * 8];
#pragma unroll
        for (int j = 0; j < 8; j++)
            dst[j] = f2bf(W[(kbase + j) * HD + col]);
    }
    __syncthreads();

    const int wave = tid >> 6, lane = tid & 63;
    const int quad = lane >> 4, rl = lane & 15;
    const int row0 = blockIdx.x * 64 + wave * 16;
    const int crow = min(row0 + rl, N_NODES - 1);

    short8 a[4];
    const float* xp = x + (size_t)crow * IN_DIM + quad * 8;
#pragma unroll
    for (int kc = 0; kc < 4; kc++) {
        float4 v0 = *(const float4*)(xp + kc * 32);
        float4 v1 = *(const float4*)(xp + kc * 32 + 4);
        short8 av;
        av[0] = (short)f2bf(v0.x); av[1] = (short)f2bf(v0.y);
        av[2] = (short)f2bf(v0.z); av[3] = (short)f2bf(v0.w);
        av[4] = (short)f2bf(v1.x); av[5] = (short)f2bf(v1.y);
        av[6] = (short)f2bf(v1.z); av[7] = (short)f2bf(v1.w);
        a[kc] = av;
    }

    float asv[8], atv[8];
#pragma unroll
    for (int nt = 0; nt < 8; nt++) {
        asv[nt] = a_src[nt * 16 + rl];
        atv[nt] = a_tgt[nt * 16 + rl];
    }

    float ps[4][4], pt[4][4];   // [head][r]
#pragma unroll
    for (int hh = 0; hh < 4; hh++)
#pragma unroll
        for (int r = 0; r < 4; r++) { ps[hh][r] = 0.f; pt[hh][r] = 0.f; }

#pragma unroll
    for (int nt = 0; nt < 8; nt++) {
        f32x4 acc = {0.f, 0.f, 0.f, 0.f};
#pragma unroll
        for (int kc = 0; kc < 4; kc++) {
            short8 b = *(const short8*)&Wl[((nt * 4 + kc) * 64 + lane) * 8];
            acc = __builtin_amdgcn_mfma_f32_16x16x32_bf16(a[kc], b, acc, 0, 0, 0);
        }
        const int ocol = nt * 16 + rl;
        const int hh   = nt >> 1;
#pragma unroll
        for (int r = 0; r < 4; r++) {
            int orow = row0 + quad * 4 + r;
            if (orow < N_NODES)
                hb[(size_t)orow * HD + ocol] = f2bf(acc[r]);
            ps[hh][r] = fmaf(acc[r], asv[nt], ps[hh][r]);
            pt[hh][r] = fmaf(acc[r], atv[nt], pt[hh][r]);
        }
    }

#pragma unroll
    for (int m = 1; m <= 8; m <<= 1) {
#pragma unroll
        for (int hh = 0; hh < 4; hh++)
#pragma unroll
            for (int r = 0; r < 4; r++) {
                ps[hh][r] += __shfl_xor(ps[hh][r], m, 64);
                pt[hh][r] += __shfl_xor(pt[hh][r], m, 64);
            }
    }
    if (rl == 0) {
#pragma unroll
        for (int r = 0; r < 4; r++) {
            int orow = row0 + quad * 4 + r;
            if (orow < N_NODES) {
#pragma unroll
                for (int hh = 0; hh < 4; hh++) {
                    s[orow * HEADS + hh] = ps[hh][r];
                    t[orow * HEADS + hh] = pt[hh][r];
                }
            }
        }
    }
}

// ============================================================
// F2: fused bucket fine-sort (blocks 0..NB-1) || per-head node max
// (blocks NB..NB+K2_BLOCKS-1). Independent inputs, forced overlap.
// ============================================================
struct SortSh {
    int ebl[PCAP]; int csc[NB + 1];
    int deg_l[128]; int excl_l[128]; int cur_l[128];
    int wtot;
};                                                             // ~13.3 KB
union F2Sh { SortSh so; float red[4][8]; };

__global__ __launch_bounds__(256) void f2_sort_max(
    const int* __restrict__ bcur, const int* __restrict__ ebkt,
    int* __restrict__ rowptr, unsigned short* __restrict__ esrc,
    const float* __restrict__ s, const float* __restrict__ t,
    unsigned* __restrict__ smax, unsigned* __restrict__ tmax)
{
    __shared__ F2Sh sh;
    int tid  = threadIdx.x;
    int lane = tid & 63, wv = tid >> 6;

    if (blockIdx.x >= NB) {
        // ---------------- node-max path ----------------
        int bI = blockIdx.x - NB;
        float sm0 = -INFINITY, sm1 = -INFINITY, sm2 = -INFINITY, sm3 = -INFINITY;
        float tm0 = -INFINITY, tm1 = -INFINITY, tm2 = -INFINITY, tm3 = -INFINITY;
        for (int n = bI * 256 + tid; n < N_NODES; n += K2_BLOCKS * 256) {
            float4 s4 = ((const float4*)s)[n];
            float4 t4 = ((const float4*)t)[n];
            sm0 = fmaxf(sm0, s4.x); sm1 = fmaxf(sm1, s4.y);
            sm2 = fmaxf(sm2, s4.z); sm3 = fmaxf(sm3, s4.w);
            tm0 = fmaxf(tm0, t4.x); tm1 = fmaxf(tm1, t4.y);
            tm2 = fmaxf(tm2, t4.z); tm3 = fmaxf(tm3, t4.w);
        }
#pragma unroll
        for (int m = 32; m >= 1; m >>= 1) {
            sm0 = fmaxf(sm0, __shfl_xor(sm0, m, 64));
            sm1 = fmaxf(sm1, __shfl_xor(sm1, m, 64));
            sm2 = fmaxf(sm2, __shfl_xor(sm2, m, 64));
            sm3 = fmaxf(sm3, __shfl_xor(sm3, m, 64));
            tm0 = fmaxf(tm0, __shfl_xor(tm0, m, 64));
            tm1 = fmaxf(tm1, __shfl_xor(tm1, m, 64));
            tm2 = fmaxf(tm2, __shfl_xor(tm2, m, 64));
            tm3 = fmaxf(tm3, __shfl_xor(tm3, m, 64));
        }
        if (lane == 0) {
            sh.red[wv][0] = sm0; sh.red[wv][1] = sm1;
            sh.red[wv][2] = sm2; sh.red[wv][3] = sm3;
            sh.red[wv][4] = tm0; sh.red[wv][5] = tm1;
            sh.red[wv][6] = tm2; sh.red[wv][7] = tm3;
        }
        __syncthreads();
        if (tid < 8) {
            float v = fmaxf(fmaxf(sh.red[0][tid], sh.red[1][tid]),
                            fmaxf(sh.red[2][tid], sh.red[3][tid]));
            unsigned* dst = (tid < 4) ? &smax[tid] : &tmax[tid - 4];
            atomicMax(dst, enc_max(v));
        }
        return;
    }

    // ---------------- bucket fine-sort path ----------------
    int b = blockIdx.x;
    int* ebl    = sh.so.ebl;
    int* csc    = sh.so.csc;
    int* deg_l  = sh.so.deg_l;
    int* excl_l = sh.so.excl_l;
    int* cur_l  = sh.so.cur_l;

    for (int i = tid; i < NB; i += 256) csc[i] = min(bcur[i], PCAP);
    if (tid < 128) { deg_l[tid] = 0; cur_l[tid] = 0; }
    __syncthreads();
    // wave-0 chunked exclusive scan of csc[0..NB)
    if (tid < 64) {
        int cb = tid * SCCH;
        int loc[SCCH];
        int sum = 0;
#pragma unroll
        for (int k = 0; k < SCCH; k++) {
            int idx = cb + k;
            int v = (idx < NB) ? csc[idx] : 0;
            loc[k] = sum; sum += v;
        }
        int ss = sum;
#pragma unroll
        for (int off = 1; off < 64; off <<= 1) {
            int u = __shfl_up(ss, off, 64);
            if (tid >= off) ss += u;
        }
        int excl = ss - sum;
#pragma unroll
        for (int k = 0; k < SCCH; k++) {
            int idx = cb + k;
            if (idx < NB) csc[idx] = excl + loc[k];
        }
        if (tid == 63) {
            csc[NB] = excl + sum;             // == E_EDGES
            if (b == 0) rowptr[N_NODES] = excl + sum;
        }
    }
    __syncthreads();
    int base_in = b * PCAP;
    int base    = csc[b];
    int cnt     = csc[b + 1] - base;          // <= PCAP

    // stage + per-target degree histogram
    for (int j = tid; j < cnt; j += 256) {
        int p = ebkt[base_in + j];
        ebl[j] = p;
        atomicAdd(&deg_l[p >> 16], 1);
    }
    __syncthreads();

    // exclusive scan of 128 target degrees
    int v = (tid < 128) ? deg_l[tid] : 0;
    int sv2 = v;
#pragma unroll
    for (int off = 1; off < 64; off <<= 1) {
        int u = __shfl_up(sv2, off, 64);
        if (lane >= off) sv2 += u;
    }
    if (tid == 63) sh.so.wtot = sv2;
    __syncthreads();
    if (tid < 128) {
        int ex = sv2 - v + ((wv == 1) ? sh.so.wtot : 0);
        excl_l[tid] = ex;
        int node = (b << BSH) + tid;
        if (node < N_NODES) rowptr[node] = base + ex;
    }
    __syncthreads();
    for (int j = tid; j < cnt; j += 256) {
        int p  = ebl[j];
        int tl = p >> 16;
        int off = atomicAdd(&cur_l[tl], 1);
        esrc[base + excl_l[tl] + off] = (unsigned short)(p & 0xFFFF);
    }
}

// ============================================================
// K4: pull aggregation (R5-verified form). 16 lanes per node, 8 bf16
// ch each; per edge the 16 lanes read one contiguous 256B hb row.
// Barrier-free, atomic-free (R2: block sync poison; R8: 3.2M global
// atomics = +96us). 8-wide edge chunks with clamped tail; dual accums.
// ============================================================
__global__ __launch_bounds__(256) void k4_pull(
    const int* __restrict__ rowptr, const unsigned short* __restrict__ esrc,
    const float* __restrict__ s, const float* __restrict__ t,
    const unsigned* __restrict__ smax, const unsigned* __restrict__ tmax,
    const unsigned short* __restrict__ hb, unsigned short* __restrict__ outpb)
{
    int g = blockIdx.x * 256 + threadIdx.x;
    int node = g >> 4;
    int lane = g & 15;
    int head = lane >> 2;                 // 4 lanes per head, 8 ch each
    int beg = rowptr[node];
    int end = rowptr[node + 1];
    float mx = leaky(dec_max(smax[head]) + dec_max(tmax[head]));
    float tv = t[node * HEADS + head];

    float p0 = 0.f, p1 = 0.f, p2 = 0.f, p3 = 0.f;
    float p4 = 0.f, p5 = 0.f, p6 = 0.f, p7 = 0.f, psum = 0.f;
    float q0 = 0.f, q1 = 0.f, q2 = 0.f, q3 = 0.f;
    float q4 = 0.f, q5 = 0.f, q6 = 0.f, q7 = 0.f, qsum = 0.f;
    const unsigned short* hbase = hb + lane * 8;

    for (int j = beg; j < end; j += 8) {
        int lim = end - j;                // >= 1
        int si[8];
#pragma unroll
        for (int u = 0; u < 8; u++) {
            int uu = (u < lim) ? u : (lim - 1);
            si[u] = __builtin_nontemporal_load(&esrc[j + uu]);
        }
        float sv[8];
        us8 hv[8];
#pragma unroll
        for (int u = 0; u < 8; u++) {
            sv[u] = s[si[u] * HEADS + head];
            hv[u] = *(const us8*)(hbase + (size_t)si[u] * HD);
        }
        float al[8];
#pragma unroll
        for (int u = 0; u < 8; u++) {
            float a = __expf(leaky(sv[u] + tv) - mx);
            al[u] = (u < lim) ? a : 0.f;
        }
#pragma unroll
        for (int u = 0; u < 8; u += 2) {
            float a0 = al[u], a1 = al[u + 1];
            p0 = fmaf(a0, bf2f(hv[u][0]), p0);  q0 = fmaf(a1, bf2f(hv[u+1][0]), q0);
            p1 = fmaf(a0, bf2f(hv[u][1]), p1);  q1 = fmaf(a1, bf2f(hv[u+1][1]), q1);
            p2 = fmaf(a0, bf2f(hv[u][2]), p2);  q2 = fmaf(a1, bf2f(hv[u+1][2]), q2);
            p3 = fmaf(a0, bf2f(hv[u][3]), p3);  q3 = fmaf(a1, bf2f(hv[u+1][3]), q3);
            p4 = fmaf(a0, bf2f(hv[u][4]), p4);  q4 = fmaf(a1, bf2f(hv[u+1][4]), q4);
            p5 = fmaf(a0, bf2f(hv[u][5]), p5);  q5 = fmaf(a1, bf2f(hv[u+1][5]), q5);
            p6 = fmaf(a0, bf2f(hv[u][6]), p6);  q6 = fmaf(a1, bf2f(hv[u+1][6]), q6);
            p7 = fmaf(a0, bf2f(hv[u][7]), p7);  q7 = fmaf(a1, bf2f(hv[u+1][7]), q7);
            psum += a0; qsum += a1;
        }
    }

    float w = 1.0f / (psum + qsum + 1e-16f);
    us8 o;
    o[0] = f2bf((p0 + q0) * w); o[1] = f2bf((p1 + q1) * w);
    o[2] = f2bf((p2 + q2) * w); o[3] = f2bf((p3 + q3) * w);
    o[4] = f2bf((p4 + q4) * w); o[5] = f2bf((p5 + q5) * w);
    o[6] = f2bf((p6 + q6) * w); o[7] = f2bf((p7 + q7) * w);
    *(us8*)(outpb + (size_t)node * HD + lane * 8) = o;
}

// ============================================================
// K5: BN stats. WIDENED: 782 blocks x 64 rows (was 196 x 256 =
// 0.77 blocks/CU -- a streaming pass can't reach BW at <1 block/CU).
// Per-block LDS reduce -> NPART partial arrays (24 serialized
// adds/address; R8 lesson caps atomic chain length).
// ============================================================
__global__ __launch_bounds__(256) void k5_stats(
    const unsigned short* __restrict__ outpb,
    float* __restrict__ bnp_sum, float* __restrict__ bnp_sq)
{
    __shared__ float lsum[HD], lsq[HD];
    int c8  = threadIdx.x & 15;          // channel octet
    int grp = threadIdx.x >> 4;          // row subgroup 0..15
    if (threadIdx.x < HD) { lsum[threadIdx.x] = 0.f; lsq[threadIdx.x] = 0.f; }
    __syncthreads();
    int base = blockIdx.x * 64;
    int end  = min(base + 64, N_NODES);
    float sm[8], sq[8];
#pragma unroll
    for (int i = 0; i < 8; i++) { sm[i] = 0.f; sq[i] = 0.f; }
    for (int r = base + grp; r < end; r += 16) {
        us8 v = *(const us8*)(outpb + (size_t)r * HD + c8 * 8);
#pragma unroll
        for (int i = 0; i < 8; i++) {
            float f = bf2f(v[i]);
            sm[i] += f;
            sq[i] = fmaf(f, f, sq[i]);
        }
    }
#pragma unroll
    for (int i = 0; i < 8; i++) {
        atomicAdd(&lsum[c8 * 8 + i], sm[i]);
        atomicAdd(&lsq[c8 * 8 + i], sq[i]);
    }
    __syncthreads();
    if (threadIdx.x < HD) {
        int ps = blockIdx.x & (NPART - 1);
        unsafeAtomicAdd(&bnp_sum[ps * HD + threadIdx.x], lsum[threadIdx.x]);
        unsafeAtomicAdd(&bnp_sq [ps * HD + threadIdx.x], lsq[threadIdx.x]);
    }
}

// ============================================================
// K6: BN apply (bf16 in, fp32 out). WIDENED: 782 blocks x 64 rows.
// Prologue collapses the NPART partials (L2-hot) into scale/shift.
// ============================================================
__global__ __launch_bounds__(256) void k6_apply(
    const unsigned short* __restrict__ outpb,
    const float* __restrict__ bnp_sum, const float* __restrict__ bnp_sq,
    const float* __restrict__ gamma, const float* __restrict__ beta,
    float* __restrict__ out)
{
    __shared__ float scs[HD], shs[HD];
    int tid = threadIdx.x;
    if (tid < HD) {
        float sm = 0.f, sq = 0.f;
#pragma unroll 4
        for (int p = 0; p < NPART; p++) {
            sm += bnp_sum[p * HD + tid];
            sq += bnp_sq [p * HD + tid];
        }
        float inv_n = 1.0f / (float)N_NODES;
        float mean = sm * inv_n;
        float var  = sq * inv_n - mean * mean;
        float sc   = gamma[tid] * rsqrtf(var + BN_EPS);
        scs[tid] = sc;
        shs[tid] = beta[tid] - mean * sc;
    }
    __syncthreads();

    int c8  = tid & 15;
    int grp = tid >> 4;
    float scale[8], shift[8];
#pragma unroll
    for (int i = 0; i < 8; i++) {
        scale[i] = scs[c8 * 8 + i];
        shift[i] = shs[c8 * 8 + i];
    }
    int base = blockIdx.x * 64;
    int end  = min(base + 64, N_NODES);
    for (int r = base + grp; r < end; r += 16) {
        us8 v = *(const us8*)(outpb + (size_t)r * HD + c8 * 8);
        float4 o0, o1;
        o0.x = fmaf(bf2f(v[0]), scale[0], shift[0]);
        o0.y = fmaf(bf2f(v[1]), scale[1], shift[1]);
        o0.z = fmaf(bf2f(v[2]), scale[2], shift[2]);
        o0.w = fmaf(bf2f(v[3]), scale[3], shift[3]);
        o1.x = fmaf(bf2f(v[4]), scale[4], shift[4]);
        o1.y = fmaf(bf2f(v[5]), scale[5], shift[5]);
        o1.z = fmaf(bf2f(v[6]), scale[6], shift[6]);
        o1.w = fmaf(bf2f(v[7]), scale[7], shift[7]);
        float* op = out + (size_t)r * HD + c8 * 8;
        ((float4*)op)[0] = o0;
        ((float4*)op)[1] = o1;
    }
}

// ============================================================
extern "C" void kernel_launch(void* const* d_in, const int* in_sizes, int n_in,
                              void* d_out, int out_size, void* d_ws, size_t ws_size,
                              hipStream_t stream)
{
    const float* x     = (const float*)d_in[0];
    const float* W     = (const float*)d_in[1];
    const float* a_src = (const float*)d_in[2];
    const float* a_tgt = (const float*)d_in[3];
    const float* gamma = (const float*)d_in[4];
    const float* beta  = (const float*)d_in[5];
    const int*   eidx  = (const int*)d_in[6];
    const int* src = eidx;
    const int* tgt = eidx + E_EDGES;
    float* out = (float*)d_out;

    // workspace layout
    unsigned short* hb    = (unsigned short*)d_ws;          // 6.4M ushort
    float*          s     = (float*)d_ws + 3200000;         // 200K float
    float*          t     = s + (size_t)N_NODES * HEADS;    // 200K float
    unsigned short* outpb = (unsigned short*)(t + (size_t)N_NODES * HEADS); // 6.4M us
    int*            ebkt  = (int*)outpb;                    // NB*PCAP=1.0M int (aliases outpb)
    unsigned short* esrc  = outpb + 6400000;                // 800K ushort
    int*            rowptr= (int*)(esrc + E_EDGES);         // 50,001 int
    // ---- zero-init region (single memset) ----
    int*      bcur  = rowptr + N_NODES + 1;                 // 392
    unsigned* smax  = (unsigned*)(bcur + 392);              // 4
    unsigned* tmax  = smax + 4;                             // 4
    float*    bnp_sum = (float*)(tmax + 4);                 // 64*128
    float*    bnp_sq  = bnp_sum + NPART * HD;               // 64*128
    size_t zero_bytes = (392 + 8 + 2 * NPART * HD) * 4;     // ~67 KB
    hipMemsetAsync(bcur, 0, zero_bytes, stream);

    // F1: GEMM || edge bucketing (independent inputs, forced overlap)
    f1_gemm_fill<<<K1B + FB, 256, 0, stream>>>(x, W, a_src, a_tgt,
                                               src, tgt, bcur, ebkt,
                                               hb, s, t);
    // F2: bucket fine-sort || per-head node max
    f2_sort_max<<<NB + K2_BLOCKS, 256, 0, stream>>>(bcur, ebkt, rowptr, esrc,
                                                    s, t, smax, tmax);
    // pull aggregation (no atomics, no barriers), bf16 h gather, bf16 out
    k4_pull<<<(N_NODES * 16) / 256, 256, 0, stream>>>(
        rowptr, esrc, s, t, smax, tmax, hb, outpb);
    // BN stats (782 blocks, partial arrays)
    k5_stats<<<BNB, 256, 0, stream>>>(outpb, bnp_sum, bnp_sq);
    // BN apply (collapses partials in prologue)
    k6_apply<<<BNB, 256, 0, stream>>>(outpb, bnp_sum, bnp_sq,
                                      gamma, beta, out);
}

// Round 11
// 176.969 us; speedup vs baseline: 4.8457x; 1.0657x over previous
//
#include <hip/hip_runtime.h>
#include <math.h>

#define N_NODES 50000
#define E_EDGES 800000
#define IN_DIM 128
#define HEADS 4
#define OUT_DIM 32
#define HD 128          // HEADS*OUT_DIM
#define LEAKY 0.4f
#define BN_EPS 1e-5f

// bucketed counting sort params: bucket = tgt >> 7 (128 targets/bucket)
#define BSH 7
#define NB ((N_NODES + 127) >> BSH)     // 391
#define FB 196                           // fill block count
#define FCH 4096                         // edges per fill block
#define PCAP 2560                        // padded bucket capacity (mean 2048, sd 45)
#define SCCH ((NB + 63) / 64)            // 7: scan chunk per lane
#define K1B ((N_NODES + 63) / 64)        // 782 GEMM blocks
#define K2_BLOCKS 32

typedef __attribute__((ext_vector_type(8))) short short8;
typedef __attribute__((ext_vector_type(8))) unsigned short us8;
typedef __attribute__((ext_vector_type(4))) float f32x4;

// ---- monotonic float<->uint encoding for atomicMax on floats ----
__device__ __forceinline__ unsigned enc_max(float f) {
    unsigned u = __float_as_uint(f);
    return ((int)u >= 0) ? (u | 0x80000000u) : ~u;
}
__device__ __forceinline__ float dec_max(unsigned u) {
    return (u & 0x80000000u) ? __uint_as_float(u ^ 0x80000000u)
                             : __uint_as_float(~u);
}

__device__ __forceinline__ float leaky(float v) {
    return v > 0.f ? v : LEAKY * v;
}

// fp32 -> bf16 (round-to-nearest-even), finite inputs
__device__ __forceinline__ unsigned short f2bf(float f) {
    unsigned u = __float_as_uint(f);
    u = (u + 0x7FFFu + ((u >> 16) & 1u)) >> 16;
    return (unsigned short)u;
}
__device__ __forceinline__ float bf2f(unsigned short u) {
    return __uint_as_float(((unsigned)u) << 16);
}

// ============================================================
// F1: fused GEMM (blocks 0..K1B-1) || edge bucketing (blocks K1B..).
// Disjoint inputs; fusion forces concurrent execution (R3: worth
// ~17-21us vs serial dispatches).
// Fill path does an IN-LDS counting sort by bucket before writing
// ebkt (coalesced run writes). This is the exact R5-measured kernel
// (178.1us) -- best verified configuration of this session.
// Closed avenues (measured): per-head k4 split (+30us, occupancy),
// cooperative launch (graph-capture fail), spin grid barrier
// (+640us, poll storm), BN fusion via LDS (+45us) or global atomics
// (+88us), k5/k6 widening (+10us, per-block overhead dominates).
// ============================================================
struct FillSh {
    int est[FCH];                 // staged packed edges (src | tgt<<16)
    int srt[FCH];                 // bucket-sorted copy
    int hist[NB];                 // count -> cursor
    int lsc[NB];                  // exclusive scan (preserved)
    int rbase[NB];                // reserved global run base
};                                // ~36.8 KB
union F1Sh { unsigned short Wl[32 * 64 * 8]; FillSh fl; };

__global__ __launch_bounds__(256) void f1_gemm_fill(
    const float* __restrict__ x, const float* __restrict__ W,
    const float* __restrict__ a_src, const float* __restrict__ a_tgt,
    const int* __restrict__ src, const int* __restrict__ tgt,
    int* __restrict__ bcur, int* __restrict__ ebkt,
    unsigned short* __restrict__ hb, float* __restrict__ s,
    float* __restrict__ t)
{
    __shared__ F1Sh sh;
    const int tid = threadIdx.x;

    if (blockIdx.x >= K1B) {
        // ---------------- fill path ----------------
        int* est   = sh.fl.est;
        int* srt   = sh.fl.srt;
        int* hist  = sh.fl.hist;
        int* lsc   = sh.fl.lsc;
        int* rbase = sh.fl.rbase;
        int beg = (blockIdx.x - K1B) * FCH;
        int cnt = min(beg + FCH, E_EDGES) - beg;
        for (int i = tid; i < NB; i += 256) hist[i] = 0;
        __syncthreads();
        for (int j = tid; j < cnt; j += 256) {
            int sv = src[beg + j], tv = tgt[beg + j];   // both < 65536
            est[j] = sv | (tv << 16);
            atomicAdd(&hist[tv >> BSH], 1);
        }
        __syncthreads();
        // reserve global runs + wave-0 exclusive scan of hist
        for (int i = tid; i < NB; i += 256) {
            int c = hist[i];
            if (c) {
                int r = atomicAdd(&bcur[i], c);
                rbase[i] = i * PCAP + min(r, PCAP);
            }
        }
        if (tid < 64) {
            int cb = tid * SCCH;
            int loc[SCCH];
            int sum = 0;
#pragma unroll
            for (int k = 0; k < SCCH; k++) {
                int idx = cb + k;
                int v = (idx < NB) ? hist[idx] : 0;
                loc[k] = sum; sum += v;
            }
            int ss = sum;
#pragma unroll
            for (int off = 1; off < 64; off <<= 1) {
                int u = __shfl_up(ss, off, 64);
                if (tid >= off) ss += u;
            }
            int excl = ss - sum;
#pragma unroll
            for (int k = 0; k < SCCH; k++) {
                int idx = cb + k;
                if (idx < NB) lsc[idx] = excl + loc[k];
            }
        }
        __syncthreads();
        // cursor init + LDS scatter into bucket-sorted order
        for (int i = tid; i < NB; i += 256) hist[i] = lsc[i];
        __syncthreads();
        for (int j = tid; j < cnt; j += 256) {
            int p = est[j];
            int pos = atomicAdd(&hist[(int)((unsigned)p >> 16) >> BSH], 1);
            srt[pos] = p;
        }
        __syncthreads();
        // coalesced run writes: consecutive tids -> adjacent addresses
        for (int j = tid; j < cnt; j += 256) {
            int p  = srt[j];
            int tv = (int)((unsigned)p >> 16);
            int b  = tv >> BSH;
            int idx = rbase[b] + (j - lsc[b]);
            if (idx < (b + 1) * PCAP)             // overflow guard (never hits)
                ebkt[idx] = (p & 0xFFFF) | ((tv & 127) << 16);
        }
        return;
    }

    // ---------------- GEMM path ----------------
    // W staged into LDS pre-swizzled into B-fragment layout (32 KB).
    unsigned short* Wl = sh.Wl;
    for (int idx = tid; idx < 2048; idx += 256) {
        int l  = idx & 63;
        int f  = idx >> 6;
        int nt = f >> 2, kc = f & 3;
        int kbase = kc * 32 + ((l >> 4) << 3);
        int col   = nt * 16 + (l & 15);
        unsigned short* dst = &Wl[idx * 8];
#pragma unroll
        for (int j = 0; j < 8; j++)
            dst[j] = f2bf(W[(kbase + j) * HD + col]);
    }
    __syncthreads();

    const int wave = tid >> 6, lane = tid & 63;
    const int quad = lane >> 4, rl = lane & 15;
    const int row0 = blockIdx.x * 64 + wave * 16;
    const int crow = min(row0 + rl, N_NODES - 1);

    short8 a[4];
    const float* xp = x + (size_t)crow * IN_DIM + quad * 8;
#pragma unroll
    for (int kc = 0; kc < 4; kc++) {
        float4 v0 = *(const float4*)(xp + kc * 32);
        float4 v1 = *(const float4*)(xp + kc * 32 + 4);
        short8 av;
        av[0] = (short)f2bf(v0.x); av[1] = (short)f2bf(v0.y);
        av[2] = (short)f2bf(v0.z); av[3] = (short)f2bf(v0.w);
        av[4] = (short)f2bf(v1.x); av[5] = (short)f2bf(v1.y);
        av[6] = (short)f2bf(v1.z); av[7] = (short)f2bf(v1.w);
        a[kc] = av;
    }

    float asv[8], atv[8];
#pragma unroll
    for (int nt = 0; nt < 8; nt++) {
        asv[nt] = a_src[nt * 16 + rl];
        atv[nt] = a_tgt[nt * 16 + rl];
    }

    float ps[4][4], pt[4][4];   // [head][r]
#pragma unroll
    for (int hh = 0; hh < 4; hh++)
#pragma unroll
        for (int r = 0; r < 4; r++) { ps[hh][r] = 0.f; pt[hh][r] = 0.f; }

#pragma unroll
    for (int nt = 0; nt < 8; nt++) {
        f32x4 acc = {0.f, 0.f, 0.f, 0.f};
#pragma unroll
        for (int kc = 0; kc < 4; kc++) {
            short8 b = *(const short8*)&Wl[((nt * 4 + kc) * 64 + lane) * 8];
            acc = __builtin_amdgcn_mfma_f32_16x16x32_bf16(a[kc], b, acc, 0, 0, 0);
        }
        const int ocol = nt * 16 + rl;
        const int hh   = nt >> 1;
#pragma unroll
        for (int r = 0; r < 4; r++) {
            int orow = row0 + quad * 4 + r;
            if (orow < N_NODES)
                hb[(size_t)orow * HD + ocol] = f2bf(acc[r]);
            ps[hh][r] = fmaf(acc[r], asv[nt], ps[hh][r]);
            pt[hh][r] = fmaf(acc[r], atv[nt], pt[hh][r]);
        }
    }

#pragma unroll
    for (int m = 1; m <= 8; m <<= 1) {
#pragma unroll
        for (int hh = 0; hh < 4; hh++)
#pragma unroll
            for (int r = 0; r < 4; r++) {
                ps[hh][r] += __shfl_xor(ps[hh][r], m, 64);
                pt[hh][r] += __shfl_xor(pt[hh][r], m, 64);
            }
    }
    if (rl == 0) {
#pragma unroll
        for (int r = 0; r < 4; r++) {
            int orow = row0 + quad * 4 + r;
            if (orow < N_NODES) {
#pragma unroll
                for (int hh = 0; hh < 4; hh++) {
                    s[orow * HEADS + hh] = ps[hh][r];
                    t[orow * HEADS + hh] = pt[hh][r];
                }
            }
        }
    }
}

// ============================================================
// F2: fused bucket fine-sort (blocks 0..NB-1) || per-head node max
// (blocks NB..NB+K2_BLOCKS-1). Src coarse sort removed (R4: provably
// dead -- the per-target scatter destroys src order).
// ============================================================
struct SortSh {
    int ebl[PCAP]; int csc[NB + 1];
    int deg_l[128]; int excl_l[128]; int cur_l[128];
    int wtot;
};                                                             // ~13.3 KB
union F2Sh { SortSh so; float red[4][8]; };

__global__ __launch_bounds__(256) void f2_sort_max(
    const int* __restrict__ bcur, const int* __restrict__ ebkt,
    int* __restrict__ rowptr, unsigned short* __restrict__ esrc,
    const float* __restrict__ s, const float* __restrict__ t,
    unsigned* __restrict__ smax, unsigned* __restrict__ tmax)
{
    __shared__ F2Sh sh;
    int tid  = threadIdx.x;
    int lane = tid & 63, wv = tid >> 6;

    if (blockIdx.x >= NB) {
        // ---------------- node-max path ----------------
        int bI = blockIdx.x - NB;
        float sm0 = -INFINITY, sm1 = -INFINITY, sm2 = -INFINITY, sm3 = -INFINITY;
        float tm0 = -INFINITY, tm1 = -INFINITY, tm2 = -INFINITY, tm3 = -INFINITY;
        for (int n = bI * 256 + tid; n < N_NODES; n += K2_BLOCKS * 256) {
            float4 s4 = ((const float4*)s)[n];
            float4 t4 = ((const float4*)t)[n];
            sm0 = fmaxf(sm0, s4.x); sm1 = fmaxf(sm1, s4.y);
            sm2 = fmaxf(sm2, s4.z); sm3 = fmaxf(sm3, s4.w);
            tm0 = fmaxf(tm0, t4.x); tm1 = fmaxf(tm1, t4.y);
            tm2 = fmaxf(tm2, t4.z); tm3 = fmaxf(tm3, t4.w);
        }
#pragma unroll
        for (int m = 32; m >= 1; m >>= 1) {
            sm0 = fmaxf(sm0, __shfl_xor(sm0, m, 64));
            sm1 = fmaxf(sm1, __shfl_xor(sm1, m, 64));
            sm2 = fmaxf(sm2, __shfl_xor(sm2, m, 64));
            sm3 = fmaxf(sm3, __shfl_xor(sm3, m, 64));
            tm0 = fmaxf(tm0, __shfl_xor(tm0, m, 64));
            tm1 = fmaxf(tm1, __shfl_xor(tm1, m, 64));
            tm2 = fmaxf(tm2, __shfl_xor(tm2, m, 64));
            tm3 = fmaxf(tm3, __shfl_xor(tm3, m, 64));
        }
        if (lane == 0) {
            sh.red[wv][0] = sm0; sh.red[wv][1] = sm1;
            sh.red[wv][2] = sm2; sh.red[wv][3] = sm3;
            sh.red[wv][4] = tm0; sh.red[wv][5] = tm1;
            sh.red[wv][6] = tm2; sh.red[wv][7] = tm3;
        }
        __syncthreads();
        if (tid < 8) {
            float v = fmaxf(fmaxf(sh.red[0][tid], sh.red[1][tid]),
                            fmaxf(sh.red[2][tid], sh.red[3][tid]));
            unsigned* dst = (tid < 4) ? &smax[tid] : &tmax[tid - 4];
            atomicMax(dst, enc_max(v));
        }
        return;
    }

    // ---------------- bucket fine-sort path ----------------
    int b = blockIdx.x;
    int* ebl    = sh.so.ebl;
    int* csc    = sh.so.csc;
    int* deg_l  = sh.so.deg_l;
    int* excl_l = sh.so.excl_l;
    int* cur_l  = sh.so.cur_l;

    for (int i = tid; i < NB; i += 256) csc[i] = min(bcur[i], PCAP);
    if (tid < 128) { deg_l[tid] = 0; cur_l[tid] = 0; }
    __syncthreads();
    // wave-0 chunked exclusive scan of csc[0..NB)
    if (tid < 64) {
        int cb = tid * SCCH;
        int loc[SCCH];
        int sum = 0;
#pragma unroll
        for (int k = 0; k < SCCH; k++) {
            int idx = cb + k;
            int v = (idx < NB) ? csc[idx] : 0;
            loc[k] = sum; sum += v;
        }
        int ss = sum;
#pragma unroll
        for (int off = 1; off < 64; off <<= 1) {
            int u = __shfl_up(ss, off, 64);
            if (tid >= off) ss += u;
        }
        int excl = ss - sum;
#pragma unroll
        for (int k = 0; k < SCCH; k++) {
            int idx = cb + k;
            if (idx < NB) csc[idx] = excl + loc[k];
        }
        if (tid == 63) {
            csc[NB] = excl + sum;             // == E_EDGES
            if (b == 0) rowptr[N_NODES] = excl + sum;
        }
    }
    __syncthreads();
    int base_in = b * PCAP;
    int base    = csc[b];
    int cnt     = csc[b + 1] - base;          // <= PCAP

    // stage + per-target degree histogram
    for (int j = tid; j < cnt; j += 256) {
        int p = ebkt[base_in + j];
        ebl[j] = p;
        atomicAdd(&deg_l[p >> 16], 1);
    }
    __syncthreads();

    // exclusive scan of 128 target degrees
    int v = (tid < 128) ? deg_l[tid] : 0;
    int sv2 = v;
#pragma unroll
    for (int off = 1; off < 64; off <<= 1) {
        int u = __shfl_up(sv2, off, 64);
        if (lane >= off) sv2 += u;
    }
    if (tid == 63) sh.so.wtot = sv2;
    __syncthreads();
    if (tid < 128) {
        int ex = sv2 - v + ((wv == 1) ? sh.so.wtot : 0);
        excl_l[tid] = ex;
        int node = (b << BSH) + tid;
        if (node < N_NODES) rowptr[node] = base + ex;
    }
    __syncthreads();
    for (int j = tid; j < cnt; j += 256) {
        int p  = ebl[j];
        int tl = p >> 16;
        int off = atomicAdd(&cur_l[tl], 1);
        esrc[base + excl_l[tl] + off] = (unsigned short)(p & 0xFFFF);
    }
}

// ============================================================
// K4: pull aggregation, monolithic (R4: per-head split starves
// occupancy). 16 lanes per node, 8 bf16 ch each; per edge the 16
// lanes read one contiguous 256B hb row (4 lines, 100% utilized).
// Barrier-free, atomic-free (R2: block sync poison; R8: global-atomic
// stats poison). NT hints on esrc (read-once) and outpb (write stream).
// ============================================================
__global__ __launch_bounds__(256) void k4_pull(
    const int* __restrict__ rowptr, const unsigned short* __restrict__ esrc,
    const float* __restrict__ s, const float* __restrict__ t,
    const unsigned* __restrict__ smax, const unsigned* __restrict__ tmax,
    const unsigned short* __restrict__ hb, unsigned short* __restrict__ outpb)
{
    int g = blockIdx.x * 256 + threadIdx.x;
    int node = g >> 4;
    int lane = g & 15;
    if (node >= N_NODES) return;
    int head = lane >> 2;                 // 4 lanes per head, 8 ch each
    int beg = rowptr[node];
    int end = rowptr[node + 1];
    float mx = leaky(dec_max(smax[head]) + dec_max(tmax[head]));
    float tv = t[node * HEADS + head];

    float p0 = 0.f, p1 = 0.f, p2 = 0.f, p3 = 0.f;
    float p4 = 0.f, p5 = 0.f, p6 = 0.f, p7 = 0.f, psum = 0.f;
    float q0 = 0.f, q1 = 0.f, q2 = 0.f, q3 = 0.f;
    float q4 = 0.f, q5 = 0.f, q6 = 0.f, q7 = 0.f, qsum = 0.f;
    const unsigned short* hbase = hb + lane * 8;

    for (int j = beg; j < end; j += 8) {
        int lim = end - j;                // >= 1
        int si[8];
#pragma unroll
        for (int u = 0; u < 8; u++) {
            int uu = (u < lim) ? u : (lim - 1);
            si[u] = __builtin_nontemporal_load(&esrc[j + uu]);
        }
        float sv[8];
        us8 hv[8];
#pragma unroll
        for (int u = 0; u < 8; u++) {
            sv[u] = s[si[u] * HEADS + head];
            hv[u] = *(const us8*)(hbase + (size_t)si[u] * HD);
        }
        float al[8];
#pragma unroll
        for (int u = 0; u < 8; u++) {
            float a = __expf(leaky(sv[u] + tv) - mx);
            al[u] = (u < lim) ? a : 0.f;
        }
#pragma unroll
        for (int u = 0; u < 8; u += 2) {
            float a0 = al[u], a1 = al[u + 1];
            p0 = fmaf(a0, bf2f(hv[u][0]), p0);  q0 = fmaf(a1, bf2f(hv[u+1][0]), q0);
            p1 = fmaf(a0, bf2f(hv[u][1]), p1);  q1 = fmaf(a1, bf2f(hv[u+1][1]), q1);
            p2 = fmaf(a0, bf2f(hv[u][2]), p2);  q2 = fmaf(a1, bf2f(hv[u+1][2]), q2);
            p3 = fmaf(a0, bf2f(hv[u][3]), p3);  q3 = fmaf(a1, bf2f(hv[u+1][3]), q3);
            p4 = fmaf(a0, bf2f(hv[u][4]), p4);  q4 = fmaf(a1, bf2f(hv[u+1][4]), q4);
            p5 = fmaf(a0, bf2f(hv[u][5]), p5);  q5 = fmaf(a1, bf2f(hv[u+1][5]), q5);
            p6 = fmaf(a0, bf2f(hv[u][6]), p6);  q6 = fmaf(a1, bf2f(hv[u+1][6]), q6);
            p7 = fmaf(a0, bf2f(hv[u][7]), p7);  q7 = fmaf(a1, bf2f(hv[u+1][7]), q7);
            psum += a0; qsum += a1;
        }
    }

    float w = 1.0f / (psum + qsum + 1e-16f);
    us8 o;
    o[0] = f2bf((p0 + q0) * w); o[1] = f2bf((p1 + q1) * w);
    o[2] = f2bf((p2 + q2) * w); o[3] = f2bf((p3 + q3) * w);
    o[4] = f2bf((p4 + q4) * w); o[5] = f2bf((p5 + q5) * w);
    o[6] = f2bf((p6 + q6) * w); o[7] = f2bf((p7 + q7) * w);
    __builtin_nontemporal_store(o, (us8*)(outpb + (size_t)node * HD + lane * 8));
}

// ============================================================
// K5: BN stats from bf16 outp: per-channel sum & sumsq (196 blocks;
// R10 showed widening costs +10us -- per-block overhead dominates).
// ============================================================
__global__ __launch_bounds__(256) void k5_stats(
    const unsigned short* __restrict__ outpb,
    float* __restrict__ bnsum, float* __restrict__ bnsq)
{
    __shared__ float lsum[HD], lsq[HD];
    int c8  = threadIdx.x & 15;          // channel octet
    int grp = threadIdx.x >> 4;          // row subgroup 0..15
    if (threadIdx.x < HD) { lsum[threadIdx.x] = 0.f; lsq[threadIdx.x] = 0.f; }
    __syncthreads();
    int base = blockIdx.x * 256;
    int end  = min(base + 256, N_NODES);
    float sm[8], sq[8];
#pragma unroll
    for (int i = 0; i < 8; i++) { sm[i] = 0.f; sq[i] = 0.f; }
    for (int r = base + grp; r < end; r += 16) {
        us8 v = *(const us8*)(outpb + (size_t)r * HD + c8 * 8);
#pragma unroll
        for (int i = 0; i < 8; i++) {
            float f = bf2f(v[i]);
            sm[i] += f;
            sq[i] = fmaf(f, f, sq[i]);
        }
    }
#pragma unroll
    for (int i = 0; i < 8; i++) {
        atomicAdd(&lsum[c8 * 8 + i], sm[i]);
        atomicAdd(&lsq[c8 * 8 + i], sq[i]);
    }
    __syncthreads();
    if (threadIdx.x < HD) {
        unsafeAtomicAdd(&bnsum[threadIdx.x], lsum[threadIdx.x]);
        unsafeAtomicAdd(&bnsq[threadIdx.x], lsq[threadIdx.x]);
    }
}

// ============================================================
// K6: BN apply (bf16 in, fp32 out) -> d_out
// ============================================================
__global__ __launch_bounds__(256) void k6_apply(
    const unsigned short* __restrict__ outpb,
    const float* __restrict__ bnsum, const float* __restrict__ bnsq,
    const float* __restrict__ gamma, const float* __restrict__ beta,
    float* __restrict__ out)
{
    int c8  = threadIdx.x & 15;
    int grp = threadIdx.x >> 4;
    int base = blockIdx.x * 256;
    int end  = min(base + 256, N_NODES);
    float inv_n = 1.0f / (float)N_NODES;
    float scale[8], shift[8];
#pragma unroll
    for (int i = 0; i < 8; i++) {
        int c = c8 * 8 + i;
        float mean = bnsum[c] * inv_n;
        float var  = bnsq[c] * inv_n - mean * mean;
        float sc   = gamma[c] * rsqrtf(var + BN_EPS);
        scale[i] = sc;
        shift[i] = beta[c] - mean * sc;
    }
    for (int r = base + grp; r < end; r += 16) {
        us8 v = *(const us8*)(outpb + (size_t)r * HD + c8 * 8);
        float4 o0, o1;
        o0.x = fmaf(bf2f(v[0]), scale[0], shift[0]);
        o0.y = fmaf(bf2f(v[1]), scale[1], shift[1]);
        o0.z = fmaf(bf2f(v[2]), scale[2], shift[2]);
        o0.w = fmaf(bf2f(v[3]), scale[3], shift[3]);
        o1.x = fmaf(bf2f(v[4]), scale[4], shift[4]);
        o1.y = fmaf(bf2f(v[5]), scale[5], shift[5]);
        o1.z = fmaf(bf2f(v[6]), scale[6], shift[6]);
        o1.w = fmaf(bf2f(v[7]), scale[7], shift[7]);
        float* op = out + (size_t)r * HD + c8 * 8;
        ((float4*)op)[0] = o0;
        ((float4*)op)[1] = o1;
    }
}

// ============================================================
extern "C" void kernel_launch(void* const* d_in, const int* in_sizes, int n_in,
                              void* d_out, int out_size, void* d_ws, size_t ws_size,
                              hipStream_t stream)
{
    const float* x     = (const float*)d_in[0];
    const float* W     = (const float*)d_in[1];
    const float* a_src = (const float*)d_in[2];
    const float* a_tgt = (const float*)d_in[3];
    const float* gamma = (const float*)d_in[4];
    const float* beta  = (const float*)d_in[5];
    const int*   eidx  = (const int*)d_in[6];
    const int* src = eidx;
    const int* tgt = eidx + E_EDGES;
    float* out = (float*)d_out;

    // workspace layout
    unsigned short* hb    = (unsigned short*)d_ws;          // 6.4M ushort
    float*          s     = (float*)d_ws + 3200000;         // 200K float
    float*          t     = s + (size_t)N_NODES * HEADS;    // 200K float
    unsigned short* outpb = (unsigned short*)(t + (size_t)N_NODES * HEADS); // 6.4M us
    int*            ebkt  = (int*)outpb;                    // NB*PCAP=1.0M int (aliases outpb)
    unsigned short* esrc  = outpb + 6400000;                // 800K ushort
    int*            rowptr= (int*)(esrc + E_EDGES);         // 50,001 int
    // ---- zero-init region (single memset) ----
    int*      bcur  = rowptr + N_NODES + 1;                 // 392
    unsigned* smax  = (unsigned*)(bcur + 392);              // 4
    unsigned* tmax  = smax + 4;                             // 4
    float*    bnsum = (float*)(tmax + 4);                   // 128
    float*    bnsq  = bnsum + HD;                           // 128
    size_t zero_bytes = (392 + 8 + HD + HD) * 4;
    hipMemsetAsync(bcur, 0, zero_bytes, stream);

    // F1: GEMM || edge bucketing (independent inputs, forced overlap)
    f1_gemm_fill<<<K1B + FB, 256, 0, stream>>>(x, W, a_src, a_tgt,
                                               src, tgt, bcur, ebkt,
                                               hb, s, t);
    // F2: bucket fine-sort || per-head node max
    f2_sort_max<<<NB + K2_BLOCKS, 256, 0, stream>>>(bcur, ebkt, rowptr, esrc,
                                                    s, t, smax, tmax);
    // pull aggregation (no atomics, no barriers), bf16 h gather, bf16 out
    long long k4_threads = (long long)N_NODES * 16;
    k4_pull<<<(unsigned)((k4_threads + 255) / 256), 256, 0, stream>>>(
        rowptr, esrc, s, t, smax, tmax, hb, outpb);
    // BN
    k5_stats<<<(N_NODES + 255) / 256, 256, 0, stream>>>(outpb, bnsum, bnsq);
    k6_apply<<<(N_NODES + 255) / 256, 256, 0, stream>>>(outpb, bnsum, bnsq,
                                                        gamma, beta, out);
}